// Round 14
// baseline (149.757 us; speedup 1.0000x reference)
//
#include <hip/hip_runtime.h>

#define IMG 256
#define TW 32
#define TH 32
#define TILES 64           // 8x8 tiles
#define SUBSPLIT 16        // scan-fallback substreams per tile
#define NRB 2048           // raster blocks (equal virtual-stream split)
#define BIGF 1e30f

typedef float v4f __attribute__((ext_vector_type(4)));

__device__ __forceinline__ float ndc(int i) { return (2.0f*i + 1.0f - IMG) * (1.0f/IMG); }

// center-out ring walk (fallback raster only)
__device__ __forceinline__ void rank_to_tile(int rank, int& tx, int& ty) {
    int k, base;
    if (rank < 4)       { k = 0; base = 0;  }
    else if (rank < 16) { k = 1; base = 4;  }
    else if (rank < 36) { k = 2; base = 16; }
    else                { k = 3; base = 36; }
    int j = rank - base;
    int s = 2*k + 2;
    int seg = j / (s - 1);
    int off = j - seg * (s - 1);
    int lo = 3 - k, hi = 4 + k;
    if      (seg == 0) { tx = lo + off; ty = lo; }
    else if (seg == 1) { tx = hi;       ty = lo + off; }
    else if (seg == 2) { tx = hi - off; ty = hi; }
    else               { tx = lo;       ty = hi - off; }
}

// conservative rect-vs-face test (edges 0..2): max of edge plane over rect corners
__device__ __forceinline__ bool tile_test(v4f gx, v4f gy, v4f a,
                                          float txlo, float txhi, float tylo, float tyhi) {
    float m0 = fmaxf(gx.x*txlo, gx.x*txhi) + fmaxf(gy.x*tylo, gy.x*tyhi) + a.x;
    float m1 = fmaxf(gx.y*txlo, gx.y*txhi) + fmaxf(gy.y*tylo, gy.y*tyhi) + a.y;
    float m2 = fmaxf(gx.z*txlo, gx.z*txhi) + fmaxf(gy.z*tylo, gy.z*tyhi) + a.z;
    return fminf(fminf(m0, m1), m2) >= -1e-5f;
}

// min of affine plane over pixel-center rect
__device__ __forceinline__ float plane_min(float gw, float hw, float aw,
                                           float xlo, float xhi, float ylo, float yhi) {
    return fminf(gw*xlo, gw*xhi) + fminf(hw*ylo, hw*yhi) + aw;
}

// full-wave (64-lane) max via DPP — VALU-pipe only (R5-proven)
__device__ __forceinline__ float wave_max_dpp(float v) {
    int x;
    x = __builtin_amdgcn_update_dpp(0, __float_as_int(v), 0x111, 0xF, 0xF, true);
    v = fmaxf(v, __int_as_float(x));
    x = __builtin_amdgcn_update_dpp(0, __float_as_int(v), 0x112, 0xF, 0xF, true);
    v = fmaxf(v, __int_as_float(x));
    x = __builtin_amdgcn_update_dpp(0, __float_as_int(v), 0x114, 0xF, 0xF, true);
    v = fmaxf(v, __int_as_float(x));
    x = __builtin_amdgcn_update_dpp(0, __float_as_int(v), 0x118, 0xF, 0xF, true);
    v = fmaxf(v, __int_as_float(x));
    x = __builtin_amdgcn_update_dpp(0, __float_as_int(v), 0x142, 0xF, 0xF, true);
    v = fmaxf(v, __int_as_float(x));
    x = __builtin_amdgcn_update_dpp(0, __float_as_int(v), 0x143, 0xF, 0xF, true);
    v = fmaxf(v, __int_as_float(x));
    return __int_as_float(__builtin_amdgcn_readlane(__float_as_int(v), 63));
}

// conservative tile-cover mask (bit t = ty*8+tx) from pixel bbox + edge tests
__device__ __forceinline__ unsigned long long cover_mask_px(int i0, int i1, int j0, int j1,
                                                            v4f gx, v4f gy, v4f aa) {
    if (i0 > 255 || i1 < 0 || j0 > 255 || j1 < 0) return 0ull;
    int tx0 = max(i0, 0) >> 5, tx1 = min(i1, 255) >> 5;
    int ty0 = max(j0, 0) >> 5, ty1 = min(j1, 255) >> 5;
    unsigned long long m = 0ull;
    for (int ty = ty0; ty <= ty1; ++ty) {
        float tylo = ndc(ty*TH), tyhi = ndc(ty*TH + TH - 1);
        for (int tx = tx0; tx <= tx1; ++tx) {
            if (tile_test(gx, gy, aa, ndc(tx*TW), ndc(tx*TW + TW - 1), tylo, tyhi))
                m |= 1ull << (ty*8 + tx);
        }
    }
    return m;
}

// ---------------- fused prep (R14: 64-thread face blocks) | out init ----------
// 1 face/thread, 64 faces/block -> 625 blocks (was 157 of 256): all CUs active
// (R13 diagnosis: prep was grid-starved at 0.6 blocks/CU, 30us for ~3us work).
// Bin regions fixed: ids[bin*F..), len in gcnt[bin]. Entry packed:
// id | (blo<<28) | (bhi<<30) (y-band range). Single class (near/far dropped).
__global__ __launch_bounds__(64) void k_prep(const float* __restrict__ verts,
                       const int* __restrict__ faces,
                       const float* __restrict__ Km, const float* __restrict__ Rm,
                       const float* __restrict__ tm, const float* __restrict__ dm,
                       v4f* __restrict__ fd, v4f* __restrict__ bb,
                       unsigned int* __restrict__ ids,
                       unsigned int* __restrict__ outz, unsigned int* __restrict__ gcnt,
                       int B, int V, int F, int nz, int faceBlocks, int doBins) {
    if ((int)blockIdx.x >= faceBlocks) {
        int idx = (blockIdx.x - faceBlocks) * 64 + threadIdx.x;
        int stride = (gridDim.x - faceBlocks) * 64;
        for (int j = idx; j < nz; j += stride) outz[j] = 0x42C80000u;  // 100.0f (far)
        return;
    }
    __shared__ int lcnt[1024];
    __shared__ unsigned int lbase[1024];
    __shared__ int lofs[1024];
    int nbins = TILES * B;
    int tid = threadIdx.x;
    if (doBins) {
        for (int k = tid; k < nbins; k += 64) { lcnt[k] = 0; lofs[k] = 0; }
        __syncthreads();
    }
    int i = blockIdx.x * 64 + tid;
    bool alive = i < B * F;
    unsigned long long tmask = 0ull;
    int b = 0, j0c = 0, j1c = 0;
    if (alive) {
        b = i / F;
        const float* vb = verts + (size_t)b * V * 3;
        const float* R = Rm + b * 9;
        const float* K = Km + b * 9;
        const float* t = tm + b * 3;
        const float* d = dm + b * 5;
        float X[3], Y[3], Z[3];
        #pragma unroll
        for (int c = 0; c < 3; ++c) {
            int vi = faces[3*i + c];
            float px = vb[3*vi], py = vb[3*vi+1], pz = vb[3*vi+2];
            float x = R[0]*px + R[1]*py + R[2]*pz + t[0];
            float y = R[3]*px + R[4]*py + R[5]*pz + t[1];
            float z = R[6]*px + R[7]*py + R[8]*pz + t[2];
            float iz = 1.0f / (z + 1e-9f);
            float x_ = x * iz, y_ = y * iz;
            float k1 = d[0], k2 = d[1], p1 = d[2], p2 = d[3], k3 = d[4];
            float r2 = x_*x_ + y_*y_;
            float rad = 1.0f + k1*r2 + k2*r2*r2 + k3*r2*r2*r2;
            float xd = x_*rad + 2.0f*p1*x_*y_ + p2*(r2 + 2.0f*x_*x_);
            float yd = y_*rad + p1*(r2 + 2.0f*y_*y_) + 2.0f*p2*x_*y_;
            float u  = K[0]*xd + K[1]*yd + K[2];
            float vc = K[3]*xd + K[4]*yd + K[5];
            vc = 1024.0f - vc;
            X[c] = (u  - 512.0f) * (1.0f/512.0f);
            Y[c] = (vc - 512.0f) * (1.0f/512.0f);
            Z[c] = z;
        }
        float x0=X[0], y0=Y[0], z0=Z[0], x1=X[1], y1=Y[1], z1=Z[1], x2=X[2], y2=Y[2], z2=Z[2];
        float denom = (y1-y2)*(x0-x2) + (x2-x1)*(y0-y2);
        bool ok = (fabsf(denom) > 1e-8f) && (z0 > 1e-8f) && (z1 > 1e-8f) && (z2 > 1e-8f);
        if (!ok) {
            bb[i] = (v4f){3e38f, -3e38f, 3e38f, -3e38f};
        } else {
            float s = (denom > 0.0f) ? 1.0f : -1.0f;
            float absd = fabsf(denom);
            float P0x = s*(y1-y2), P0y = s*(x2-x1);
            float P1x = s*(y2-y0), P1y = s*(x0-x2);
            float P2x = -(P0x + P1x), P2y = -(P0y + P1y);
            float A0 = -(P0x*x2 + P0y*y2);
            float A1 = -(P1x*x2 + P1y*y2);
            float A2 = absd - A0 - A1;
            float ia  = 1.0f / absd;
            float rz0 = ia / z0, rz1 = ia / z1, rz2 = ia / z2;
            float zix = P0x*rz0 + P1x*rz1 + P2x*rz2;
            float ziy = P0y*rz0 + P1y*rz1 + P2y*rz2;
            float zic = A0*rz0 + A1*rz1 + A2*rz2;
            v4f ga = (v4f){P0x, P1x, P2x, -zix};
            v4f gb = (v4f){P0y, P1y, P2y, -ziy};
            v4f gc = (v4f){A0,  A1,  A2,  10.0f - zic};
            fd[(size_t)i*3 + 0] = ga;
            fd[(size_t)i*3 + 1] = gb;
            fd[(size_t)i*3 + 2] = gc;
            float xmn = fminf(x0, fminf(x1, x2)) - 1e-4f;
            float xmx = fmaxf(x0, fmaxf(x1, x2)) + 1e-4f;
            float ymn = fminf(y0, fminf(y1, y2)) - 1e-4f;
            float ymx = fmaxf(y0, fmaxf(y1, y2)) + 1e-4f;
            bb[i] = (v4f){xmn, xmx, ymn, ymx};
            if (doBins) {
                int i0 = (int)floorf(xmn*128.0f + 127.5f);
                int i1 = (int)ceilf (xmx*128.0f + 127.5f);
                int j0 = (int)floorf(ymn*128.0f + 127.5f);
                int j1 = (int)ceilf (ymx*128.0f + 127.5f);
                tmask = cover_mask_px(i0, i1, j0, j1, ga, gb, gc);
                j0c = max(j0, 0); j1c = min(j1, 255);
            }
        }
    }
    if (doBins) {
        unsigned long long mk = tmask;
        while (mk) {
            int t = __builtin_ctzll(mk); mk &= mk - 1ull;
            atomicAdd(&lcnt[t*B + b], 1);
        }
        __syncthreads();
        for (int k = tid; k < nbins; k += 64)
            if (lcnt[k]) lbase[k] = atomicAdd(&gcnt[k], (unsigned int)lcnt[k]);
        __syncthreads();
        mk = tmask;
        while (mk) {
            int t = __builtin_ctzll(mk); mk &= mk - 1ull;
            int ty = t >> 3;
            int bin = t*B + b;
            unsigned int blo = (unsigned int)max((j0c >> 3) - ty*4, 0);
            unsigned int bhi = (unsigned int)min((j1c >> 3) - ty*4, 3);
            unsigned int pack = (unsigned int)i | (blo << 28) | (bhi << 30);
            int sl = atomicAdd(&lofs[bin], 1);
            ids[(size_t)bin*F + lbase[bin] + sl] = pack;
        }
    }
}

// ---------------- exclusive prefix over bins (1 block) ------------------------
__global__ __launch_bounds__(256) void k_scan(const unsigned int* __restrict__ gcnt,
                                              unsigned int* __restrict__ goff, int nbins) {
    __shared__ unsigned int ps[256];
    int tid = threadIdx.x;
    unsigned int loc[4], s = 0;
    #pragma unroll
    for (int k = 0; k < 4; ++k) {
        int idx = tid*4 + k;
        unsigned int c = (idx < nbins) ? gcnt[idx] : 0u;
        loc[k] = c; s += c;
    }
    ps[tid] = s; __syncthreads();
    #pragma unroll
    for (int d = 1; d < 256; d <<= 1) {
        unsigned int t = (tid >= d) ? ps[tid - d] : 0u;
        __syncthreads();
        ps[tid] += t;
        __syncthreads();
    }
    unsigned int run = ps[tid] - s;
    #pragma unroll
    for (int k = 0; k < 4; ++k) {
        int idx = tid*4 + k;
        if (idx < nbins) {
            goff[idx] = run; run += loc[k];
            if (idx == nbins - 1) goff[nbins] = run;
        }
    }
}

// ---------------- binned band raster (R14: equal virtual-stream split) --------
// The global id stream (bins concatenated via goff prefix) is split into NRB
// EQUAL slices; block k binary-searches its start bin and walks bins within
// its slice, running the R10-proven body per bin. Max block work ~= mean
// -> tail collapses (R11's unit-table failed on granularity: 1100 units for
// 2048 slots; this gives exactly one slice per block). Output exact: min
// commutative, per-(block,bin) hi-Z seed conservative.
__global__ __launch_bounds__(256) void k_raster(const v4f* __restrict__ fd,
                                                const unsigned int* __restrict__ ids,
                                                const unsigned int* __restrict__ goff,
                                                unsigned int* __restrict__ outz,
                                                int B, int F, int nbins) {
    __shared__ v4f sA[257], sB[257], sC[257];
    int tid = threadIdx.x, lane = tid & 63, wave = tid >> 6;
    int wbase = wave << 6;
    unsigned int T = goff[nbins];
    if (T == 0) return;
    unsigned int g0 = (unsigned int)(((unsigned long long)blockIdx.x     * T) / NRB);
    unsigned int g1 = (unsigned int)(((unsigned long long)(blockIdx.x+1) * T) / NRB);
    if (g1 <= g0) return;

    // binary search: largest bin with goff[bin] <= g0
    int lo = 0, hi = nbins;
    while (hi - lo > 1) { int mid = (lo + hi) >> 1; if (goff[mid] <= g0) lo = mid; else hi = mid; }
    int bin = lo;
    unsigned int g = g0;

    while (g < g1) {
        unsigned int boff = goff[bin], bend = goff[bin+1];
        if (bend <= boff || bend <= g) { ++bin; continue; }
        unsigned int p0 = g - boff;
        unsigned int p1 = min(bend, g1) - boff;

        int t = bin / B;
        int b = bin - t * B;
        int ty = t >> 3, tx = t & 7;
        size_t base = (size_t)bin * F;

        int rowbase = ty*TH + wave*8;
        int row = rowbase + (lane >> 3);
        int col = tx*TW + (lane & 7) * 4;
        float yp = ndc(row);
        float xp[4];
        #pragma unroll
        for (int jj = 0; jj < 4; ++jj) xp[jj] = ndc(col + jj);
        float txlo = ndc(tx*TW), txhi = ndc(tx*TW + TW - 1);
        float bylo = ndc(rowbase), byhi = ndc(rowbase + 7);
        float m[4] = {BIGF, BIGF, BIGF, BIGF};

        int orow = IMG - 1 - row;
        size_t zo = (size_t)b * (IMG*IMG) + (size_t)orow * IMG + col;

        // hi-Z seed from current output (any published value is a valid bound)
        float hs = 0.0f;
        #pragma unroll
        for (int jj = 0; jj < 4; ++jj) {
            float d = __uint_as_float(outz[zo + jj]);
            hs = fmaxf(hs, 10.0f - 1.0f/d);
        }
        float h = fminf(9.99f, wave_max_dpp(hs) + 1e-4f);

        unsigned int pc = ids[base + min(p0 + lane, p1 - 1)];
        bool vc = (p0 + lane) < p1;
        unsigned int pn = ids[base + min(p0 + 64 + lane, p1 - 1)];
        bool vn = (p0 + 64 + lane) < p1;

        for (unsigned int p = p0; p < p1; p += 64) {
            unsigned int p2w = ids[base + min(p + 128 + lane, p1 - 1)];
            bool v2 = (p + 128 + lane) < p1;

            // band test from packed word: 2 int compares, no memory
            unsigned int blo = (pc >> 28) & 3u, bhi = pc >> 30;
            unsigned int idc = pc & 0x0FFFFFFFu;
            bool pass = vc & ((int)blo <= wave) & ((int)bhi >= wave);
            bool full = false;
            v4f ra = (v4f){0,0,0,0}, rb = (v4f){0,0,0,0}, rc = (v4f){0,0,0,0};
            if (pass) {
                ra = fd[(size_t)idc*3]; rb = fd[(size_t)idc*3+1]; rc = fd[(size_t)idc*3+2];
                float p0l=ra.x*txlo, p0h=ra.x*txhi, q0l=rb.x*bylo, q0h=rb.x*byhi;
                float p1l=ra.y*txlo, p1h=ra.y*txhi, q1l=rb.y*bylo, q1h=rb.y*byhi;
                float p2l=ra.z*txlo, p2h=ra.z*txhi, q2l=rb.z*bylo, q2h=rb.z*byhi;
                float c0x = fmaxf(p0l,p0h) + fmaxf(q0l,q0h) + rc.x;
                float c1x = fmaxf(p1l,p1h) + fmaxf(q1l,q1h) + rc.y;
                float c2x = fmaxf(p2l,p2h) + fmaxf(q2l,q2h) + rc.z;
                float c0n = fminf(p0l,p0h) + fminf(q0l,q0h) + rc.x;
                float c1n = fminf(p1l,p1h) + fminf(q1l,q1h) + rc.y;
                float c2n = fminf(p2l,p2h) + fminf(q2l,q2h) + rc.z;
                float zmn = fminf(ra.w*txlo, ra.w*txhi) + fminf(rb.w*bylo, rb.w*byhi) + rc.w;
                pass = (fminf(fminf(c0x, c1x), c2x) >= -1e-5f) & (zmn < h);
                full = (fminf(fminf(c0n, c1n), c2n) >= 1e-5f);
            }
            unsigned long long mp = __ballot(pass && !full);
            unsigned long long mf = __ballot(pass && full);
            int cp = __popcll(mp);
            int cf = __popcll(mf);
            if (pass && !full) {
                int sl = wbase + __popcll(mp & ((1ull << lane) - 1ull));
                sA[sl] = ra; sB[sl] = rb; sC[sl] = rc;
            }
            // full-cover: depth-plane-only eval via readlane broadcast (no LDS)
            unsigned long long w = mf;
            while (w) {
                int l = __builtin_amdgcn_readfirstlane(__ffsll((unsigned long long)w) - 1);
                w &= w - 1ull;
                float gxw = __int_as_float(__builtin_amdgcn_readlane(__float_as_int(ra.w), l));
                float gyw = __int_as_float(__builtin_amdgcn_readlane(__float_as_int(rb.w), l));
                float aaw = __int_as_float(__builtin_amdgcn_readlane(__float_as_int(rc.w), l));
                float e3 = fmaf(gyw, yp, aaw);
                #pragma unroll
                for (int jj = 0; jj < 4; ++jj)
                    m[jj] = fminf(m[jj], fmaf(gxw, xp[jj], e3));
            }
            // partial: LDS-compacted loop (depth-1 prefetch), R5-proven body
            if (cp > 0) {
                v4f gx = sA[wbase], gy = sB[wbase], aa = sC[wbase];
                for (int i = 0; i < cp; ++i) {
                    v4f nx = sA[wbase+i+1], ny = sB[wbase+i+1], nzv = sC[wbase+i+1];
                    float e0 = fmaf(gy.x, yp, aa.x);
                    float e1 = fmaf(gy.y, yp, aa.y);
                    float e2 = fmaf(gy.z, yp, aa.z);
                    float e3 = fmaf(gy.w, yp, aa.w);
                    #pragma unroll
                    for (int jj = 0; jj < 4; ++jj) {
                        float n0 = fmaf(gx.x, xp[jj], e0);
                        float n1 = fmaf(gx.y, xp[jj], e1);
                        float n2 = fmaf(gx.z, xp[jj], e2);
                        float n3 = fmaf(gx.w, xp[jj], e3);
                        float q = fminf(fminf(n0, n1), n2);
                        m[jj] = fminf(m[jj], (q >= 0.0f) ? n3 : BIGF);
                    }
                    gx = nx; gy = ny; aa = nzv;
                }
            }
            if (cp + cf > 0)
                h = fminf(h, wave_max_dpp(fmaxf(fmaxf(m[0], m[1]), fmaxf(m[2], m[3]))));
            pc = pn; vc = vn;
            pn = p2w; vn = v2;
        }
        // epilogue for this bin: transform + row flip + filtered atomicMin
        #pragma unroll
        for (int jj = 0; jj < 4; ++jj) {
            if (m[jj] < 9.99f) {
                float depth = 1.0f / (10.0f - m[jj]);
                unsigned int mv = __float_as_uint(depth);
                unsigned int cv = outz[zo + jj];
                if (mv < cv) atomicMin(&outz[zo + jj], mv);
            }
        }
        g = min(bend, g1);
        ++bin;
    }
}

// ---------------- fallback: R5 scan raster (if ws too small for bins) ---------
__global__ __launch_bounds__(256) void k_raster_scan(const v4f* __restrict__ fd,
                                                     const v4f* __restrict__ bb,
                                                     unsigned int* __restrict__ outz,
                                                     int B, int F) {
    __shared__ v4f sA[257], sB[257], sC[257];
    int tid = threadIdx.x, lane = tid & 63, wave = tid >> 6;
    int wbase = wave << 6;
    int j = blockIdx.x >> 4;
    int s = blockIdx.x & (SUBSPLIT-1);
    int nTB = TILES * B;
    int f_begin = (s * F) / SUBSPLIT, f_end = ((s + 1) * F) / SUBSPLIT;

    #pragma unroll 1
    for (int phase = 0; phase < 2; ++phase) {
        int tb = (phase == 0) ? j : (nTB - 1 - j);
        int rank = tb / B;
        int b = tb - rank * B;
        int tx, ty;
        rank_to_tile(rank, tx, ty);
        int rowbase = ty*TH + wave*8;
        int row = rowbase + (lane >> 3);
        int col = tx*TW + (lane & 7) * 4;
        float yp = ndc(row);
        float xp[4];
        #pragma unroll
        for (int jj = 0; jj < 4; ++jj) xp[jj] = ndc(col + jj);
        float txlo = ndc(tx*TW), txhi = ndc(tx*TW + TW - 1);
        float bylo = ndc(rowbase), byhi = ndc(rowbase + 7);
        float m[4] = {BIGF, BIGF, BIGF, BIGF};
        float h = 9.99f;

        const v4f* bbp = bb + (size_t)b * F;
        const v4f* fdp = fd + (size_t)b * F * 3;

        v4f box = bbp[min(f_begin + lane, f_end - 1)];
        bool valid = (f_begin + lane) < f_end;

        for (int g0 = f_begin; g0 < f_end; g0 += 64) {
            int fn = g0 + 64 + lane;
            v4f nbox = bbp[min(fn, f_end - 1)];
            bool nvalid = fn < f_end;

            bool pass = valid &
                        (box.x <= txhi) & (box.y >= txlo) &
                        (box.z <= byhi) & (box.w >= bylo);
            v4f ra, rb, rc;
            if (pass) {
                int f = g0 + lane;
                ra = fdp[3*f]; rb = fdp[3*f+1]; rc = fdp[3*f+2];
                pass = tile_test(ra, rb, rc, txlo, txhi, bylo, byhi)
                    && (plane_min(ra.w, rb.w, rc.w, txlo, txhi, bylo, byhi) < h);
            }
            unsigned long long mk = __ballot(pass);
            int total = __popcll(mk);
            if (pass) {
                int slot = wbase + __popcll(mk & ((1ull << lane) - 1ull));
                sA[slot] = ra;
                sB[slot] = rb;
                sC[slot] = rc;
            }
            if (total > 0) {
                v4f gx = sA[wbase], gy = sB[wbase], aa = sC[wbase];
                for (int i = 0; i < total; ++i) {
                    v4f nx = sA[wbase+i+1], ny = sB[wbase+i+1], nzv = sC[wbase+i+1];
                    float e0 = fmaf(gy.x, yp, aa.x);
                    float e1 = fmaf(gy.y, yp, aa.y);
                    float e2 = fmaf(gy.z, yp, aa.z);
                    float e3 = fmaf(gy.w, yp, aa.w);
                    #pragma unroll
                    for (int jj = 0; jj < 4; ++jj) {
                        float n0 = fmaf(gx.x, xp[jj], e0);
                        float n1 = fmaf(gx.y, xp[jj], e1);
                        float n2 = fmaf(gx.z, xp[jj], e2);
                        float n3 = fmaf(gx.w, xp[jj], e3);
                        float q = fminf(fminf(n0, n1), n2);
                        m[jj] = fminf(m[jj], (q >= 0.0f) ? n3 : BIGF);
                    }
                    gx = nx; gy = ny; aa = nzv;
                }
                h = fminf(9.99f, wave_max_dpp(fmaxf(fmaxf(m[0], m[1]), fmaxf(m[2], m[3]))));
            }
            box = nbox; valid = nvalid;
        }
        int orow = IMG - 1 - row;
        size_t zo = (size_t)b * (IMG*IMG) + (size_t)orow * IMG + col;
        #pragma unroll
        for (int jj = 0; jj < 4; ++jj) {
            if (m[jj] < 9.99f) {
                float depth = 1.0f / (10.0f - m[jj]);
                unsigned int mv = __float_as_uint(depth);
                unsigned int cv = outz[zo + jj];
                if (mv < cv) atomicMin(&outz[zo + jj], mv);
            }
        }
    }
}

extern "C" void kernel_launch(void* const* d_in, const int* in_sizes, int n_in,
                              void* d_out, int out_size, void* d_ws, size_t ws_size,
                              hipStream_t stream) {
    const float* verts = (const float*)d_in[0];
    const int*   faces = (const int*)d_in[1];
    const float* Km    = (const float*)d_in[2];
    const float* Rm    = (const float*)d_in[3];
    const float* tm    = (const float*)d_in[4];
    const float* dm    = (const float*)d_in[5];
    float* out = (float*)d_out;

    int B = in_sizes[2] / 9;
    int V = in_sizes[0] / (3 * B);
    int F = in_sizes[1] / (3 * B);
    int nz = B * IMG * IMG;
    int nbins = TILES * B;

    char* ws = (char*)d_ws;
    size_t al = 255;
    size_t o_fd  = 0;
    size_t o_bb  = (o_fd + (size_t)B*F*48 + al) & ~al;
    size_t o_cnt = (o_bb + (size_t)B*F*16 + al) & ~al;
    size_t o_off = (o_cnt + (size_t)nbins*4 + al) & ~al;
    size_t o_ids = (o_off + (size_t)(nbins+1)*4 + al) & ~al;
    size_t need_bins = o_ids + (size_t)nbins * F * 4;   // fixed bin regions, exact capacity
    size_t need_scan = o_cnt;

    v4f* fd  = (v4f*)(ws + o_fd);
    v4f* bbp = (v4f*)(ws + o_bb);
    unsigned int* gcnt = (unsigned int*)(ws + o_cnt);
    unsigned int* goff = (unsigned int*)(ws + o_off);
    unsigned int* ids  = (unsigned int*)(ws + o_ids);

    int faceBlocks = (B*F + 63) / 64;

    // packed-id format requires id < 2^28
    if (ws_size >= need_bins && nbins <= 1024 && (size_t)B*F < (1u<<28)) {
        hipMemsetAsync(gcnt, 0, (size_t)nbins*4, stream);
        k_prep<<<faceBlocks + 256, 64, 0, stream>>>(verts, faces, Km, Rm, tm, dm,
                                                    fd, bbp, ids, (unsigned int*)out, gcnt,
                                                    B, V, F, nz, faceBlocks, 1);
        k_scan<<<1, 256, 0, stream>>>(gcnt, goff, nbins);
        k_raster<<<NRB, 256, 0, stream>>>(fd, ids, goff, (unsigned int*)out, B, F, nbins);
    } else if (ws_size >= need_scan) {
        k_prep<<<faceBlocks + 256, 64, 0, stream>>>(verts, faces, Km, Rm, tm, dm,
                                                    fd, bbp, ids, (unsigned int*)out, gcnt,
                                                    B, V, F, nz, faceBlocks, 0);
        int rasterBlocks = (TILES * B / 2) * SUBSPLIT;
        k_raster_scan<<<rasterBlocks, 256, 0, stream>>>(fd, bbp, (unsigned int*)out, B, F);
    }
}

// Round 15
// 125.241 us; speedup vs baseline: 1.1957x; 1.1957x over previous
//
#include <hip/hip_runtime.h>

#define IMG 256
#define TW 32
#define TH 32
#define TILES 64           // 8x8 tiles
#define SUBSPLIT 16        // scan-fallback substreams per tile
#define RSUB 8             // binned substreams per tile-b (R10-proven best)
#define ZTHR 9.5f          // near/far class threshold on depth key (10 - zinv)
#define BIGF 1e30f

typedef float v4f __attribute__((ext_vector_type(4)));

__device__ __forceinline__ float ndc(int i) { return (2.0f*i + 1.0f - IMG) * (1.0f/IMG); }

// center-out ring walk over the 8x8 tile grid: rank 0..63 -> (tx,ty)
__device__ __forceinline__ void rank_to_tile(int rank, int& tx, int& ty) {
    int k, base;
    if (rank < 4)       { k = 0; base = 0;  }
    else if (rank < 16) { k = 1; base = 4;  }
    else if (rank < 36) { k = 2; base = 16; }
    else                { k = 3; base = 36; }
    int j = rank - base;
    int s = 2*k + 2;
    int seg = j / (s - 1);
    int off = j - seg * (s - 1);
    int lo = 3 - k, hi = 4 + k;
    if      (seg == 0) { tx = lo + off; ty = lo; }
    else if (seg == 1) { tx = hi;       ty = lo + off; }
    else if (seg == 2) { tx = hi - off; ty = hi; }
    else               { tx = lo;       ty = hi - off; }
}

// conservative rect-vs-face test (edges 0..2): max of edge plane over rect corners
__device__ __forceinline__ bool tile_test(v4f gx, v4f gy, v4f a,
                                          float txlo, float txhi, float tylo, float tyhi) {
    float m0 = fmaxf(gx.x*txlo, gx.x*txhi) + fmaxf(gy.x*tylo, gy.x*tyhi) + a.x;
    float m1 = fmaxf(gx.y*txlo, gx.y*txhi) + fmaxf(gy.y*tylo, gy.y*tyhi) + a.y;
    float m2 = fmaxf(gx.z*txlo, gx.z*txhi) + fmaxf(gy.z*tylo, gy.z*tyhi) + a.z;
    return fminf(fminf(m0, m1), m2) >= -1e-5f;
}

// min of affine plane over pixel-center rect
__device__ __forceinline__ float plane_min(float gw, float hw, float aw,
                                           float xlo, float xhi, float ylo, float yhi) {
    return fminf(gw*xlo, gw*xhi) + fminf(hw*ylo, hw*yhi) + aw;
}

// full-wave (64-lane) max via DPP — VALU-pipe only (R5-proven)
__device__ __forceinline__ float wave_max_dpp(float v) {
    int x;
    x = __builtin_amdgcn_update_dpp(0, __float_as_int(v), 0x111, 0xF, 0xF, true);
    v = fmaxf(v, __int_as_float(x));
    x = __builtin_amdgcn_update_dpp(0, __float_as_int(v), 0x112, 0xF, 0xF, true);
    v = fmaxf(v, __int_as_float(x));
    x = __builtin_amdgcn_update_dpp(0, __float_as_int(v), 0x114, 0xF, 0xF, true);
    v = fmaxf(v, __int_as_float(x));
    x = __builtin_amdgcn_update_dpp(0, __float_as_int(v), 0x118, 0xF, 0xF, true);
    v = fmaxf(v, __int_as_float(x));
    x = __builtin_amdgcn_update_dpp(0, __float_as_int(v), 0x142, 0xF, 0xF, true);
    v = fmaxf(v, __int_as_float(x));
    x = __builtin_amdgcn_update_dpp(0, __float_as_int(v), 0x143, 0xF, 0xF, true);
    v = fmaxf(v, __int_as_float(x));
    return __int_as_float(__builtin_amdgcn_readlane(__float_as_int(v), 63));
}

// broadcast lane l's float to all lanes (exec-independent)
__device__ __forceinline__ float rlf(float v, int l) {
    return __int_as_float(__builtin_amdgcn_readlane(__float_as_int(v), l));
}

// conservative tile-cover mask (bit t = ty*8+tx) from pixel bbox + edge tests
__device__ __forceinline__ unsigned long long cover_mask_px(int i0, int i1, int j0, int j1,
                                                            v4f gx, v4f gy, v4f aa) {
    if (i0 > 255 || i1 < 0 || j0 > 255 || j1 < 0) return 0ull;
    int tx0 = max(i0, 0) >> 5, tx1 = min(i1, 255) >> 5;
    int ty0 = max(j0, 0) >> 5, ty1 = min(j1, 255) >> 5;
    unsigned long long m = 0ull;
    for (int ty = ty0; ty <= ty1; ++ty) {
        float tylo = ndc(ty*TH), tyhi = ndc(ty*TH + TH - 1);
        for (int tx = tx0; tx <= tx1; ++tx) {
            if (tile_test(gx, gy, aa, ndc(tx*TW), ndc(tx*TW + TW - 1), tylo, tyhi))
                m |= 1ull << (ty*8 + tx);
        }
    }
    return m;
}

// ---------------- fused prep: face setup + binning (near/far) | out init ------
// (R13-proven, unchanged) Bin region = ids[bin*F .. bin*F+F): NEAR ids (face
// depth key < ZTHR) from the FRONT, FAR ids from the BACK. Counts in
// gcnt[bin*2+{0,1}]. Entry packed: id|(blo<<28)|(bhi<<30).
__global__ void k_prep(const float* __restrict__ verts, const int* __restrict__ faces,
                       const float* __restrict__ Km, const float* __restrict__ Rm,
                       const float* __restrict__ tm, const float* __restrict__ dm,
                       v4f* __restrict__ fd, v4f* __restrict__ bb,
                       unsigned int* __restrict__ ids,
                       unsigned int* __restrict__ outz, unsigned int* __restrict__ gcnt,
                       int B, int V, int F, int nz, int faceBlocks, int doBins) {
    if ((int)blockIdx.x >= faceBlocks) {
        int idx = (blockIdx.x - faceBlocks) * 256 + threadIdx.x;
        int stride = (gridDim.x - faceBlocks) * 256;
        for (int j = idx; j < nz; j += stride) outz[j] = 0x42C80000u;  // 100.0f (far)
        return;
    }
    __shared__ int lcnt[2048];
    __shared__ unsigned int lbase[2048];
    __shared__ int lofs[2048];
    int nbins = TILES * B;
    int tid = threadIdx.x;
    if (doBins) {
        for (int k = tid; k < 2*nbins; k += 256) { lcnt[k] = 0; lofs[k] = 0; }
        __syncthreads();
    }
    int i = blockIdx.x * 256 + tid;
    bool alive = i < B * F;
    unsigned long long tmask = 0ull;
    int b = 0, j0c = 0, j1c = 0, cls = 0;
    if (alive) {
        b = i / F;
        const float* vb = verts + (size_t)b * V * 3;
        const float* R = Rm + b * 9;
        const float* K = Km + b * 9;
        const float* t = tm + b * 3;
        const float* d = dm + b * 5;
        float X[3], Y[3], Z[3];
        float maxzi = 0.0f;
        #pragma unroll
        for (int c = 0; c < 3; ++c) {
            int vi = faces[3*i + c];
            float px = vb[3*vi], py = vb[3*vi+1], pz = vb[3*vi+2];
            float x = R[0]*px + R[1]*py + R[2]*pz + t[0];
            float y = R[3]*px + R[4]*py + R[5]*pz + t[1];
            float z = R[6]*px + R[7]*py + R[8]*pz + t[2];
            float iz = 1.0f / (z + 1e-9f);
            maxzi = fmaxf(maxzi, iz);
            float x_ = x * iz, y_ = y * iz;
            float k1 = d[0], k2 = d[1], p1 = d[2], p2 = d[3], k3 = d[4];
            float r2 = x_*x_ + y_*y_;
            float rad = 1.0f + k1*r2 + k2*r2*r2 + k3*r2*r2*r2;
            float xd = x_*rad + 2.0f*p1*x_*y_ + p2*(r2 + 2.0f*x_*x_);
            float yd = y_*rad + p1*(r2 + 2.0f*y_*y_) + 2.0f*p2*x_*y_;
            float u  = K[0]*xd + K[1]*yd + K[2];
            float vc = K[3]*xd + K[4]*yd + K[5];
            vc = 1024.0f - vc;
            X[c] = (u  - 512.0f) * (1.0f/512.0f);
            Y[c] = (vc - 512.0f) * (1.0f/512.0f);
            Z[c] = z;
        }
        float x0=X[0], y0=Y[0], z0=Z[0], x1=X[1], y1=Y[1], z1=Z[1], x2=X[2], y2=Y[2], z2=Z[2];
        float denom = (y1-y2)*(x0-x2) + (x2-x1)*(y0-y2);
        bool ok = (fabsf(denom) > 1e-8f) && (z0 > 1e-8f) && (z1 > 1e-8f) && (z2 > 1e-8f);
        if (!ok) {
            bb[i] = (v4f){3e38f, -3e38f, 3e38f, -3e38f};
        } else {
            float s = (denom > 0.0f) ? 1.0f : -1.0f;
            float absd = fabsf(denom);
            float P0x = s*(y1-y2), P0y = s*(x2-x1);
            float P1x = s*(y2-y0), P1y = s*(x0-x2);
            float P2x = -(P0x + P1x), P2y = -(P0y + P1y);
            float A0 = -(P0x*x2 + P0y*y2);
            float A1 = -(P1x*x2 + P1y*y2);
            float A2 = absd - A0 - A1;
            float ia  = 1.0f / absd;
            float rz0 = ia / z0, rz1 = ia / z1, rz2 = ia / z2;
            float zix = P0x*rz0 + P1x*rz1 + P2x*rz2;
            float ziy = P0y*rz0 + P1y*rz1 + P2y*rz2;
            float zic = A0*rz0 + A1*rz1 + A2*rz2;
            v4f ga = (v4f){P0x, P1x, P2x, -zix};
            v4f gb = (v4f){P0y, P1y, P2y, -ziy};
            v4f gc = (v4f){A0,  A1,  A2,  10.0f - zic};
            fd[(size_t)i*3 + 0] = ga;
            fd[(size_t)i*3 + 1] = gb;
            fd[(size_t)i*3 + 2] = gc;
            float xmn = fminf(x0, fminf(x1, x2)) - 1e-4f;
            float xmx = fmaxf(x0, fmaxf(x1, x2)) + 1e-4f;
            float ymn = fminf(y0, fminf(y1, y2)) - 1e-4f;
            float ymx = fmaxf(y0, fmaxf(y1, y2)) + 1e-4f;
            bb[i] = (v4f){xmn, xmx, ymn, ymx};
            if (doBins) {
                int i0 = (int)floorf(xmn*128.0f + 127.5f);
                int i1 = (int)ceilf (xmx*128.0f + 127.5f);
                int j0 = (int)floorf(ymn*128.0f + 127.5f);
                int j1 = (int)ceilf (ymx*128.0f + 127.5f);
                tmask = cover_mask_px(i0, i1, j0, j1, ga, gb, gc);
                j0c = max(j0, 0); j1c = min(j1, 255);
                cls = ((10.0f - maxzi) < ZTHR) ? 0 : 1;   // 0 = near, 1 = far
            }
        }
    }
    if (doBins) {
        unsigned long long mk = tmask;
        while (mk) {
            int t = __builtin_ctzll(mk); mk &= mk - 1ull;
            atomicAdd(&lcnt[(t*B + b)*2 + cls], 1);
        }
        __syncthreads();
        for (int k = tid; k < 2*nbins; k += 256)
            if (lcnt[k]) lbase[k] = atomicAdd(&gcnt[k], (unsigned int)lcnt[k]);
        __syncthreads();
        mk = tmask;
        while (mk) {
            int t = __builtin_ctzll(mk); mk &= mk - 1ull;
            int ty = t >> 3;
            int bin = t*B + b;
            unsigned int blo = (unsigned int)max((j0c >> 3) - ty*4, 0);
            unsigned int bhi = (unsigned int)min((j1c >> 3) - ty*4, 3);
            unsigned int pack = (unsigned int)i | (blo << 28) | (bhi << 30);
            int key = bin*2 + cls;
            int sl = atomicAdd(&lofs[key], 1);
            unsigned int pos = lbase[key] + (unsigned int)sl;
            size_t idx = (cls == 0) ? ((size_t)bin*F + pos)               // near: front
                                    : ((size_t)bin*F + (F - 1) - pos);    // far: back
            ids[idx] = pack;
        }
    }
}

// ---------------- binned band raster (R15: LDS-free readlane eval) ------------
// R13 structure (RSUB=8, packed band word, front-to-back segments, outz hi-Z
// seed, per-group DPP refresh). R15: the partial-cover eval no longer goes
// through LDS compaction — each survivor's 12-float record is broadcast from
// its owning lane via v_readlane (pure ALU, zero memory latency), walking the
// ballot mask exactly like the proven full-cover path. Removes ds_write/
// ds_read/prefix/sentinels and all LDS. Same multiset of exact per-pixel
// evals -> output bit-identical.
__global__ __launch_bounds__(256) void k_raster(const v4f* __restrict__ fd,
                                                const unsigned int* __restrict__ ids,
                                                const unsigned int* __restrict__ gcnt,
                                                unsigned int* __restrict__ outz,
                                                int B, int F) {
    int tid = threadIdx.x, lane = tid & 63, wave = tid >> 6;
    int tbIdx = blockIdx.x >> 3;          // heavy-first: low rank = low bid
    int sub = blockIdx.x & (RSUB-1);
    int rank = tbIdx / B;
    int b = tbIdx - rank * B;
    int tx, ty;
    rank_to_tile(rank, tx, ty);
    int bin = (ty*8 + tx)*B + b;
    unsigned int lnN = gcnt[bin*2 + 0];
    unsigned int lnF = gcnt[bin*2 + 1];
    size_t base = (size_t)bin * F;

    int rowbase = ty*TH + wave*8;
    int row = rowbase + (lane >> 3);
    int col = tx*TW + (lane & 7) * 4;
    float yp = ndc(row);
    float xp[4];
    #pragma unroll
    for (int jj = 0; jj < 4; ++jj) xp[jj] = ndc(col + jj);
    float txlo = ndc(tx*TW), txhi = ndc(tx*TW + TW - 1);
    float bylo = ndc(rowbase), byhi = ndc(rowbase + 7);
    float m[4] = {BIGF, BIGF, BIGF, BIGF};

    int orow = IMG - 1 - row;
    size_t zo = (size_t)b * (IMG*IMG) + (size_t)orow * IMG + col;

    // hi-Z seed from current output (any published value is a valid bound)
    float hs = 0.0f;
    #pragma unroll
    for (int jj = 0; jj < 4; ++jj) {
        float d = __uint_as_float(outz[zo + jj]);
        hs = fmaxf(hs, 10.0f - 1.0f/d);
    }
    float h = fminf(9.99f, wave_max_dpp(hs) + 1e-4f);

    #pragma unroll 1
    for (int seg = 0; seg < 2; ++seg) {
        unsigned int segLen = (seg == 0) ? lnN : lnF;
        unsigned int segOff = (seg == 0) ? 0u : (unsigned int)F - lnF;
        unsigned int p0 = segOff + (unsigned int)(((unsigned long long)sub     * segLen) / RSUB);
        unsigned int p1 = segOff + (unsigned int)(((unsigned long long)(sub+1) * segLen) / RSUB);
        if (p1 <= p0) continue;

        unsigned int pc = ids[base + min(p0 + lane, p1 - 1)];
        bool vc = (p0 + lane) < p1;
        unsigned int pn = ids[base + min(p0 + 64 + lane, p1 - 1)];
        bool vn = (p0 + 64 + lane) < p1;

        for (unsigned int p = p0; p < p1; p += 64) {
            unsigned int p2w = ids[base + min(p + 128 + lane, p1 - 1)];
            bool v2 = (p + 128 + lane) < p1;

            // band test from packed word: 2 int compares, no memory
            unsigned int blo = (pc >> 28) & 3u, bhi = pc >> 30;
            unsigned int idc = pc & 0x0FFFFFFFu;
            bool pass = vc & ((int)blo <= wave) & ((int)bhi >= wave);
            bool full = false;
            v4f ra = (v4f){0,0,0,0}, rb = (v4f){0,0,0,0}, rc = (v4f){0,0,0,0};
            if (pass) {
                ra = fd[(size_t)idc*3]; rb = fd[(size_t)idc*3+1]; rc = fd[(size_t)idc*3+2];
                float p0l=ra.x*txlo, p0h=ra.x*txhi, q0l=rb.x*bylo, q0h=rb.x*byhi;
                float p1l=ra.y*txlo, p1h=ra.y*txhi, q1l=rb.y*bylo, q1h=rb.y*byhi;
                float p2l=ra.z*txlo, p2h=ra.z*txhi, q2l=rb.z*bylo, q2h=rb.z*byhi;
                float c0x = fmaxf(p0l,p0h) + fmaxf(q0l,q0h) + rc.x;
                float c1x = fmaxf(p1l,p1h) + fmaxf(q1l,q1h) + rc.y;
                float c2x = fmaxf(p2l,p2h) + fmaxf(q2l,q2h) + rc.z;
                float c0n = fminf(p0l,p0h) + fminf(q0l,q0h) + rc.x;
                float c1n = fminf(p1l,p1h) + fminf(q1l,q1h) + rc.y;
                float c2n = fminf(p2l,p2h) + fminf(q2l,q2h) + rc.z;
                float zmn = fminf(ra.w*txlo, ra.w*txhi) + fminf(rb.w*bylo, rb.w*byhi) + rc.w;
                pass = (fminf(fminf(c0x, c1x), c2x) >= -1e-5f) & (zmn < h);
                full = (fminf(fminf(c0n, c1n), c2n) >= 1e-5f);
            }
            unsigned long long mp = __ballot(pass && !full);
            unsigned long long mf = __ballot(pass && full);

            // full-cover: depth-plane-only eval via readlane broadcast
            unsigned long long w = mf;
            while (w) {
                int l = __builtin_amdgcn_readfirstlane(__ffsll((unsigned long long)w) - 1);
                w &= w - 1ull;
                float gxw = rlf(ra.w, l), gyw = rlf(rb.w, l), aaw = rlf(rc.w, l);
                float e3 = fmaf(gyw, yp, aaw);
                #pragma unroll
                for (int jj = 0; jj < 4; ++jj)
                    m[jj] = fminf(m[jj], fmaf(gxw, xp[jj], e3));
            }
            // partial-cover: full 12-float readlane broadcast, exact inside test
            w = mp;
            while (w) {
                int l = __builtin_amdgcn_readfirstlane(__ffsll((unsigned long long)w) - 1);
                w &= w - 1ull;
                float g0x = rlf(ra.x, l), g1x = rlf(ra.y, l), g2x = rlf(ra.z, l), g3x = rlf(ra.w, l);
                float g0y = rlf(rb.x, l), g1y = rlf(rb.y, l), g2y = rlf(rb.z, l), g3y = rlf(rb.w, l);
                float a0  = rlf(rc.x, l), a1  = rlf(rc.y, l), a2  = rlf(rc.z, l), a3  = rlf(rc.w, l);
                float e0 = fmaf(g0y, yp, a0);
                float e1 = fmaf(g1y, yp, a1);
                float e2 = fmaf(g2y, yp, a2);
                float e3 = fmaf(g3y, yp, a3);
                #pragma unroll
                for (int jj = 0; jj < 4; ++jj) {
                    float n0 = fmaf(g0x, xp[jj], e0);
                    float n1 = fmaf(g1x, xp[jj], e1);
                    float n2 = fmaf(g2x, xp[jj], e2);
                    float n3 = fmaf(g3x, xp[jj], e3);
                    float q = fminf(fminf(n0, n1), n2);
                    m[jj] = fminf(m[jj], (q >= 0.0f) ? n3 : BIGF);
                }
            }
            if (mp | mf)
                h = fminf(h, wave_max_dpp(fmaxf(fmaxf(m[0], m[1]), fmaxf(m[2], m[3]))));
            pc = pn; vc = vn;
            pn = p2w; vn = v2;
        }
    }
    // epilogue: transform + row flip + filtered atomicMin into d_out
    #pragma unroll
    for (int jj = 0; jj < 4; ++jj) {
        if (m[jj] < 9.99f) {
            float depth = 1.0f / (10.0f - m[jj]);
            unsigned int mv = __float_as_uint(depth);
            unsigned int cv = outz[zo + jj];
            if (mv < cv) atomicMin(&outz[zo + jj], mv);
        }
    }
}

// ---------------- fallback: R5 scan raster (if ws too small for bins) ---------
__global__ __launch_bounds__(256) void k_raster_scan(const v4f* __restrict__ fd,
                                                     const v4f* __restrict__ bb,
                                                     unsigned int* __restrict__ outz,
                                                     int B, int F) {
    __shared__ v4f sA[257], sB[257], sC[257];
    int tid = threadIdx.x, lane = tid & 63, wave = tid >> 6;
    int wbase = wave << 6;
    int j = blockIdx.x >> 4;
    int s = blockIdx.x & (SUBSPLIT-1);
    int nTB = TILES * B;
    int f_begin = (s * F) / SUBSPLIT, f_end = ((s + 1) * F) / SUBSPLIT;

    #pragma unroll 1
    for (int phase = 0; phase < 2; ++phase) {
        int tb = (phase == 0) ? j : (nTB - 1 - j);
        int rank = tb / B;
        int b = tb - rank * B;
        int tx, ty;
        rank_to_tile(rank, tx, ty);
        int rowbase = ty*TH + wave*8;
        int row = rowbase + (lane >> 3);
        int col = tx*TW + (lane & 7) * 4;
        float yp = ndc(row);
        float xp[4];
        #pragma unroll
        for (int jj = 0; jj < 4; ++jj) xp[jj] = ndc(col + jj);
        float txlo = ndc(tx*TW), txhi = ndc(tx*TW + TW - 1);
        float bylo = ndc(rowbase), byhi = ndc(rowbase + 7);
        float m[4] = {BIGF, BIGF, BIGF, BIGF};
        float h = 9.99f;

        const v4f* bbp = bb + (size_t)b * F;
        const v4f* fdp = fd + (size_t)b * F * 3;

        v4f box = bbp[min(f_begin + lane, f_end - 1)];
        bool valid = (f_begin + lane) < f_end;

        for (int g0 = f_begin; g0 < f_end; g0 += 64) {
            int fn = g0 + 64 + lane;
            v4f nbox = bbp[min(fn, f_end - 1)];
            bool nvalid = fn < f_end;

            bool pass = valid &
                        (box.x <= txhi) & (box.y >= txlo) &
                        (box.z <= byhi) & (box.w >= bylo);
            v4f ra, rb, rc;
            if (pass) {
                int f = g0 + lane;
                ra = fdp[3*f]; rb = fdp[3*f+1]; rc = fdp[3*f+2];
                pass = tile_test(ra, rb, rc, txlo, txhi, bylo, byhi)
                    && (plane_min(ra.w, rb.w, rc.w, txlo, txhi, bylo, byhi) < h);
            }
            unsigned long long mk = __ballot(pass);
            int total = __popcll(mk);
            if (pass) {
                int slot = wbase + __popcll(mk & ((1ull << lane) - 1ull));
                sA[slot] = ra;
                sB[slot] = rb;
                sC[slot] = rc;
            }
            if (total > 0) {
                v4f gx = sA[wbase], gy = sB[wbase], aa = sC[wbase];
                for (int i = 0; i < total; ++i) {
                    v4f nx = sA[wbase+i+1], ny = sB[wbase+i+1], nzv = sC[wbase+i+1];
                    float e0 = fmaf(gy.x, yp, aa.x);
                    float e1 = fmaf(gy.y, yp, aa.y);
                    float e2 = fmaf(gy.z, yp, aa.z);
                    float e3 = fmaf(gy.w, yp, aa.w);
                    #pragma unroll
                    for (int jj = 0; jj < 4; ++jj) {
                        float n0 = fmaf(gx.x, xp[jj], e0);
                        float n1 = fmaf(gx.y, xp[jj], e1);
                        float n2 = fmaf(gx.z, xp[jj], e2);
                        float n3 = fmaf(gx.w, xp[jj], e3);
                        float q = fminf(fminf(n0, n1), n2);
                        m[jj] = fminf(m[jj], (q >= 0.0f) ? n3 : BIGF);
                    }
                    gx = nx; gy = ny; aa = nzv;
                }
                h = fminf(9.99f, wave_max_dpp(fmaxf(fmaxf(m[0], m[1]), fmaxf(m[2], m[3]))));
            }
            box = nbox; valid = nvalid;
        }
        int orow = IMG - 1 - row;
        size_t zo = (size_t)b * (IMG*IMG) + (size_t)orow * IMG + col;
        #pragma unroll
        for (int jj = 0; jj < 4; ++jj) {
            if (m[jj] < 9.99f) {
                float depth = 1.0f / (10.0f - m[jj]);
                unsigned int mv = __float_as_uint(depth);
                unsigned int cv = outz[zo + jj];
                if (mv < cv) atomicMin(&outz[zo + jj], mv);
            }
        }
    }
}

extern "C" void kernel_launch(void* const* d_in, const int* in_sizes, int n_in,
                              void* d_out, int out_size, void* d_ws, size_t ws_size,
                              hipStream_t stream) {
    const float* verts = (const float*)d_in[0];
    const int*   faces = (const int*)d_in[1];
    const float* Km    = (const float*)d_in[2];
    const float* Rm    = (const float*)d_in[3];
    const float* tm    = (const float*)d_in[4];
    const float* dm    = (const float*)d_in[5];
    float* out = (float*)d_out;

    int B = in_sizes[2] / 9;
    int V = in_sizes[0] / (3 * B);
    int F = in_sizes[1] / (3 * B);
    int nz = B * IMG * IMG;
    int nbins = TILES * B;

    char* ws = (char*)d_ws;
    size_t al = 255;
    size_t o_fd  = 0;
    size_t o_bb  = (o_fd + (size_t)B*F*48 + al) & ~al;
    size_t o_cnt = (o_bb + (size_t)B*F*16 + al) & ~al;
    size_t o_ids = (o_cnt + (size_t)nbins*8 + al) & ~al;
    size_t need_bins = o_ids + (size_t)nbins * F * 4;   // fixed bin regions, exact capacity
    size_t need_scan = o_ids;

    v4f* fd  = (v4f*)(ws + o_fd);
    v4f* bbp = (v4f*)(ws + o_bb);
    unsigned int* gcnt = (unsigned int*)(ws + o_cnt);
    unsigned int* ids  = (unsigned int*)(ws + o_ids);

    const int thr = 256;
    int faceBlocks = (B*F + thr - 1) / thr;

    // packed-id format requires id < 2^28
    if (ws_size >= need_bins && nbins <= 1024 && (size_t)B*F < (1u<<28)) {
        hipMemsetAsync(gcnt, 0, (size_t)nbins*8, stream);
        k_prep<<<faceBlocks + 128, thr, 0, stream>>>(verts, faces, Km, Rm, tm, dm,
                                                     fd, bbp, ids, (unsigned int*)out, gcnt,
                                                     B, V, F, nz, faceBlocks, 1);
        int rasterBlocks = nbins * RSUB;              // B=4 -> 2048, heavy-first
        k_raster<<<rasterBlocks, thr, 0, stream>>>(fd, ids, gcnt,
                                                   (unsigned int*)out, B, F);
    } else if (ws_size >= need_scan) {
        k_prep<<<faceBlocks + 128, thr, 0, stream>>>(verts, faces, Km, Rm, tm, dm,
                                                     fd, bbp, ids, (unsigned int*)out, gcnt,
                                                     B, V, F, nz, faceBlocks, 0);
        int rasterBlocks = (TILES * B / 2) * SUBSPLIT;
        k_raster_scan<<<rasterBlocks, thr, 0, stream>>>(fd, bbp, (unsigned int*)out, B, F);
    }
}

// Round 17
// 119.254 us; speedup vs baseline: 1.2558x; 1.0502x over previous
//
#include <hip/hip_runtime.h>

#define IMG 256
#define TW 32
#define TH 32
#define TILES 64           // 8x8 tiles
#define SUBSPLIT 16        // scan-fallback substreams per tile
#define RSUB 8             // binned substreams per tile-b (R10-proven best)
#define ZTHR 9.5f          // near/far class threshold on depth key (10 - zinv)
#define BIGF 1e30f

typedef float v4f __attribute__((ext_vector_type(4)));

__device__ __forceinline__ float ndc(int i) { return (2.0f*i + 1.0f - IMG) * (1.0f/IMG); }

// center-out ring walk over the 8x8 tile grid: rank 0..63 -> (tx,ty)
__device__ __forceinline__ void rank_to_tile(int rank, int& tx, int& ty) {
    int k, base;
    if (rank < 4)       { k = 0; base = 0;  }
    else if (rank < 16) { k = 1; base = 4;  }
    else if (rank < 36) { k = 2; base = 16; }
    else                { k = 3; base = 36; }
    int j = rank - base;
    int s = 2*k + 2;
    int seg = j / (s - 1);
    int off = j - seg * (s - 1);
    int lo = 3 - k, hi = 4 + k;
    if      (seg == 0) { tx = lo + off; ty = lo; }
    else if (seg == 1) { tx = hi;       ty = lo + off; }
    else if (seg == 2) { tx = hi - off; ty = hi; }
    else               { tx = lo;       ty = hi - off; }
}

// conservative rect-vs-face test (edges 0..2): max of edge plane over rect corners
__device__ __forceinline__ bool tile_test(v4f gx, v4f gy, v4f a,
                                          float txlo, float txhi, float tylo, float tyhi) {
    float m0 = fmaxf(gx.x*txlo, gx.x*txhi) + fmaxf(gy.x*tylo, gy.x*tyhi) + a.x;
    float m1 = fmaxf(gx.y*txlo, gx.y*txhi) + fmaxf(gy.y*tylo, gy.y*tyhi) + a.y;
    float m2 = fmaxf(gx.z*txlo, gx.z*txhi) + fmaxf(gy.z*tylo, gy.z*tyhi) + a.z;
    return fminf(fminf(m0, m1), m2) >= -1e-5f;
}

// min of affine plane over pixel-center rect
__device__ __forceinline__ float plane_min(float gw, float hw, float aw,
                                           float xlo, float xhi, float ylo, float yhi) {
    return fminf(gw*xlo, gw*xhi) + fminf(hw*ylo, hw*yhi) + aw;
}

// full-wave (64-lane) max via DPP — VALU-pipe only (R5-proven)
__device__ __forceinline__ float wave_max_dpp(float v) {
    int x;
    x = __builtin_amdgcn_update_dpp(0, __float_as_int(v), 0x111, 0xF, 0xF, true);
    v = fmaxf(v, __int_as_float(x));
    x = __builtin_amdgcn_update_dpp(0, __float_as_int(v), 0x112, 0xF, 0xF, true);
    v = fmaxf(v, __int_as_float(x));
    x = __builtin_amdgcn_update_dpp(0, __float_as_int(v), 0x114, 0xF, 0xF, true);
    v = fmaxf(v, __int_as_float(x));
    x = __builtin_amdgcn_update_dpp(0, __float_as_int(v), 0x118, 0xF, 0xF, true);
    v = fmaxf(v, __int_as_float(x));
    x = __builtin_amdgcn_update_dpp(0, __float_as_int(v), 0x142, 0xF, 0xF, true);
    v = fmaxf(v, __int_as_float(x));
    x = __builtin_amdgcn_update_dpp(0, __float_as_int(v), 0x143, 0xF, 0xF, true);
    v = fmaxf(v, __int_as_float(x));
    return __int_as_float(__builtin_amdgcn_readlane(__float_as_int(v), 63));
}

// conservative tile-cover mask (bit t = ty*8+tx) from pixel bbox + edge tests
__device__ __forceinline__ unsigned long long cover_mask_px(int i0, int i1, int j0, int j1,
                                                            v4f gx, v4f gy, v4f aa) {
    if (i0 > 255 || i1 < 0 || j0 > 255 || j1 < 0) return 0ull;
    int tx0 = max(i0, 0) >> 5, tx1 = min(i1, 255) >> 5;
    int ty0 = max(j0, 0) >> 5, ty1 = min(j1, 255) >> 5;
    unsigned long long m = 0ull;
    for (int ty = ty0; ty <= ty1; ++ty) {
        float tylo = ndc(ty*TH), tyhi = ndc(ty*TH + TH - 1);
        for (int tx = tx0; tx <= tx1; ++tx) {
            if (tile_test(gx, gy, aa, ndc(tx*TW), ndc(tx*TW + TW - 1), tylo, tyhi))
                m |= 1ull << (ty*8 + tx);
        }
    }
    return m;
}

// ---------------- projection (R16: 64-thread blocks, no LDS/atomics) ----------
// The gather-heavy phase (3 random vertex loads/face) at 625 blocks ~ 2.4/CU:
// all CUs active (R13/R14 diagnosis: fused prep was grid-starved; R14's fix
// failed because it multiplied the BINNING flush atomics — so only the
// projection is re-grained; binning keeps 256-face blocks below).
// Writes fd, bb, keyz (face nearest depth key; BIGF for invalid).
// Tail blocks init outz to far.
__global__ __launch_bounds__(64) void k_proj(const float* __restrict__ verts,
                       const int* __restrict__ faces,
                       const float* __restrict__ Km, const float* __restrict__ Rm,
                       const float* __restrict__ tm, const float* __restrict__ dm,
                       v4f* __restrict__ fd, v4f* __restrict__ bb,
                       float* __restrict__ keyz, unsigned int* __restrict__ outz,
                       int B, int V, int F, int nz, int faceBlocks) {
    if ((int)blockIdx.x >= faceBlocks) {
        int idx = (blockIdx.x - faceBlocks) * 64 + threadIdx.x;
        int stride = (gridDim.x - faceBlocks) * 64;
        for (int j = idx; j < nz; j += stride) outz[j] = 0x42C80000u;  // 100.0f (far)
        return;
    }
    int i = blockIdx.x * 64 + threadIdx.x;
    if (i >= B * F) return;
    int b = i / F;
    const float* vb = verts + (size_t)b * V * 3;
    const float* R = Rm + b * 9;
    const float* K = Km + b * 9;
    const float* t = tm + b * 3;
    const float* d = dm + b * 5;
    float X[3], Y[3], Z[3];
    float maxzi = 0.0f;
    #pragma unroll
    for (int c = 0; c < 3; ++c) {
        int vi = faces[3*i + c];
        float px = vb[3*vi], py = vb[3*vi+1], pz = vb[3*vi+2];
        float x = R[0]*px + R[1]*py + R[2]*pz + t[0];
        float y = R[3]*px + R[4]*py + R[5]*pz + t[1];
        float z = R[6]*px + R[7]*py + R[8]*pz + t[2];
        float iz = 1.0f / (z + 1e-9f);
        maxzi = fmaxf(maxzi, iz);
        float x_ = x * iz, y_ = y * iz;
        float k1 = d[0], k2 = d[1], p1 = d[2], p2 = d[3], k3 = d[4];
        float r2 = x_*x_ + y_*y_;
        float rad = 1.0f + k1*r2 + k2*r2*r2 + k3*r2*r2*r2;
        float xd = x_*rad + 2.0f*p1*x_*y_ + p2*(r2 + 2.0f*x_*x_);
        float yd = y_*rad + p1*(r2 + 2.0f*y_*y_) + 2.0f*p2*x_*y_;
        float u  = K[0]*xd + K[1]*yd + K[2];
        float vc = K[3]*xd + K[4]*yd + K[5];
        vc = 1024.0f - vc;
        X[c] = (u  - 512.0f) * (1.0f/512.0f);
        Y[c] = (vc - 512.0f) * (1.0f/512.0f);
        Z[c] = z;
    }
    float x0=X[0], y0=Y[0], z0=Z[0], x1=X[1], y1=Y[1], z1=Z[1], x2=X[2], y2=Y[2], z2=Z[2];
    float denom = (y1-y2)*(x0-x2) + (x2-x1)*(y0-y2);
    bool ok = (fabsf(denom) > 1e-8f) && (z0 > 1e-8f) && (z1 > 1e-8f) && (z2 > 1e-8f);
    if (!ok) {
        bb[i] = (v4f){3e38f, -3e38f, 3e38f, -3e38f};
        keyz[i] = BIGF;
        return;
    }
    float s = (denom > 0.0f) ? 1.0f : -1.0f;
    float absd = fabsf(denom);
    float P0x = s*(y1-y2), P0y = s*(x2-x1);
    float P1x = s*(y2-y0), P1y = s*(x0-x2);
    float P2x = -(P0x + P1x), P2y = -(P0y + P1y);
    float A0 = -(P0x*x2 + P0y*y2);
    float A1 = -(P1x*x2 + P1y*y2);
    float A2 = absd - A0 - A1;
    float ia  = 1.0f / absd;
    float rz0 = ia / z0, rz1 = ia / z1, rz2 = ia / z2;
    float zix = P0x*rz0 + P1x*rz1 + P2x*rz2;
    float ziy = P0y*rz0 + P1y*rz1 + P2y*rz2;
    float zic = A0*rz0 + A1*rz1 + A2*rz2;
    fd[(size_t)i*3 + 0] = (v4f){P0x, P1x, P2x, -zix};
    fd[(size_t)i*3 + 1] = (v4f){P0y, P1y, P2y, -ziy};
    fd[(size_t)i*3 + 2] = (v4f){A0,  A1,  A2,  10.0f - zic};
    bb[i] = (v4f){fminf(x0, fminf(x1, x2)) - 1e-4f,
                  fmaxf(x0, fmaxf(x1, x2)) + 1e-4f,
                  fminf(y0, fminf(y1, y2)) - 1e-4f,
                  fmaxf(y0, fmaxf(y1, y2)) + 1e-4f};
    keyz[i] = 10.0f - maxzi;
}

// ---------------- binning (R16: 256-face blocks, R13-proven aggregation) ------
// Reads bb/fd/keyz (L2/L3-hot from k_proj). Bin region = ids[bin*F..bin*F+F):
// NEAR ids (keyz < ZTHR) from FRONT, FAR from BACK. Counts gcnt[bin*2+{0,1}].
// Entry packed: id | (blo<<28) | (bhi<<30). LDS two-phase -> one global
// atomic per (block,bin-class): flush count unchanged vs R13 (no R14 blow-up).
__global__ __launch_bounds__(256) void k_bin(const v4f* __restrict__ fd,
                      const v4f* __restrict__ bb, const float* __restrict__ keyz,
                      unsigned int* __restrict__ ids, unsigned int* __restrict__ gcnt,
                      int B, int F) {
    __shared__ int lcnt[2048];
    __shared__ unsigned int lbase[2048];
    __shared__ int lofs[2048];
    int nbins = TILES * B;
    int tid = threadIdx.x;
    for (int k = tid; k < 2*nbins; k += 256) { lcnt[k] = 0; lofs[k] = 0; }
    __syncthreads();
    int i = blockIdx.x * 256 + tid;
    bool alive = i < B * F;
    unsigned long long tmask = 0ull;
    int b = 0, j0c = 0, j1c = 0, cls = 0;
    if (alive) {
        b = i / F;
        v4f box = bb[i];
        if (box.x <= box.y) {   // valid face
            v4f ga = fd[(size_t)i*3], gb = fd[(size_t)i*3+1], gc = fd[(size_t)i*3+2];
            int i0 = (int)floorf(box.x*128.0f + 127.5f);
            int i1 = (int)ceilf (box.y*128.0f + 127.5f);
            int j0 = (int)floorf(box.z*128.0f + 127.5f);
            int j1 = (int)ceilf (box.w*128.0f + 127.5f);
            tmask = cover_mask_px(i0, i1, j0, j1, ga, gb, gc);
            j0c = max(j0, 0); j1c = min(j1, 255);
            cls = (keyz[i] < ZTHR) ? 0 : 1;   // 0 = near, 1 = far
        }
    }
    unsigned long long mk = tmask;
    while (mk) {
        int t = __builtin_ctzll(mk); mk &= mk - 1ull;
        atomicAdd(&lcnt[(t*B + b)*2 + cls], 1);
    }
    __syncthreads();
    for (int k = tid; k < 2*nbins; k += 256)
        if (lcnt[k]) lbase[k] = atomicAdd(&gcnt[k], (unsigned int)lcnt[k]);
    __syncthreads();
    mk = tmask;
    while (mk) {
        int t = __builtin_ctzll(mk); mk &= mk - 1ull;
        int ty = t >> 3;
        int bin = t*B + b;
        unsigned int blo = (unsigned int)max((j0c >> 3) - ty*4, 0);
        unsigned int bhi = (unsigned int)min((j1c >> 3) - ty*4, 3);
        unsigned int pack = (unsigned int)i | (blo << 28) | (bhi << 30);
        int key = bin*2 + cls;
        int sl = atomicAdd(&lofs[key], 1);
        unsigned int pos = lbase[key] + (unsigned int)sl;
        size_t idx = (cls == 0) ? ((size_t)bin*F + pos)               // near: front
                                : ((size_t)bin*F + (F - 1) - pos);    // far: back
        ids[idx] = pack;
    }
}

// ---------------- binned band raster (R13-proven, byte-identical) -------------
// RSUB=8 static split, packed band word, front-to-back segments carrying h/m,
// outz hi-Z seed, full-cover readlane path + partial LDS-compacted loop.
__global__ __launch_bounds__(256) void k_raster(const v4f* __restrict__ fd,
                                                const unsigned int* __restrict__ ids,
                                                const unsigned int* __restrict__ gcnt,
                                                unsigned int* __restrict__ outz,
                                                int B, int F) {
    __shared__ v4f sA[257], sB[257], sC[257];
    int tid = threadIdx.x, lane = tid & 63, wave = tid >> 6;
    int wbase = wave << 6;
    int tbIdx = blockIdx.x >> 3;          // heavy-first: low rank = low bid
    int sub = blockIdx.x & (RSUB-1);
    int rank = tbIdx / B;
    int b = tbIdx - rank * B;
    int tx, ty;
    rank_to_tile(rank, tx, ty);
    int bin = (ty*8 + tx)*B + b;
    unsigned int lnN = gcnt[bin*2 + 0];
    unsigned int lnF = gcnt[bin*2 + 1];
    size_t base = (size_t)bin * F;

    int rowbase = ty*TH + wave*8;
    int row = rowbase + (lane >> 3);
    int col = tx*TW + (lane & 7) * 4;
    float yp = ndc(row);
    float xp[4];
    #pragma unroll
    for (int jj = 0; jj < 4; ++jj) xp[jj] = ndc(col + jj);
    float txlo = ndc(tx*TW), txhi = ndc(tx*TW + TW - 1);
    float bylo = ndc(rowbase), byhi = ndc(rowbase + 7);
    float m[4] = {BIGF, BIGF, BIGF, BIGF};

    int orow = IMG - 1 - row;
    size_t zo = (size_t)b * (IMG*IMG) + (size_t)orow * IMG + col;

    // hi-Z seed from current output (any published value is a valid bound)
    float hs = 0.0f;
    #pragma unroll
    for (int jj = 0; jj < 4; ++jj) {
        float d = __uint_as_float(outz[zo + jj]);
        hs = fmaxf(hs, 10.0f - 1.0f/d);
    }
    float h = fminf(9.99f, wave_max_dpp(hs) + 1e-4f);

    #pragma unroll 1
    for (int seg = 0; seg < 2; ++seg) {
        unsigned int segLen = (seg == 0) ? lnN : lnF;
        unsigned int segOff = (seg == 0) ? 0u : (unsigned int)F - lnF;
        unsigned int p0 = segOff + (unsigned int)(((unsigned long long)sub     * segLen) / RSUB);
        unsigned int p1 = segOff + (unsigned int)(((unsigned long long)(sub+1) * segLen) / RSUB);
        if (p1 <= p0) continue;

        unsigned int pc = ids[base + min(p0 + lane, p1 - 1)];
        bool vc = (p0 + lane) < p1;
        unsigned int pn = ids[base + min(p0 + 64 + lane, p1 - 1)];
        bool vn = (p0 + 64 + lane) < p1;

        for (unsigned int p = p0; p < p1; p += 64) {
            unsigned int p2w = ids[base + min(p + 128 + lane, p1 - 1)];
            bool v2 = (p + 128 + lane) < p1;

            // band test from packed word: 2 int compares, no memory
            unsigned int blo = (pc >> 28) & 3u, bhi = pc >> 30;
            unsigned int idc = pc & 0x0FFFFFFFu;
            bool pass = vc & ((int)blo <= wave) & ((int)bhi >= wave);
            bool full = false;
            v4f ra = (v4f){0,0,0,0}, rb = (v4f){0,0,0,0}, rc = (v4f){0,0,0,0};
            if (pass) {
                ra = fd[(size_t)idc*3]; rb = fd[(size_t)idc*3+1]; rc = fd[(size_t)idc*3+2];
                float p0l=ra.x*txlo, p0h=ra.x*txhi, q0l=rb.x*bylo, q0h=rb.x*byhi;
                float p1l=ra.y*txlo, p1h=ra.y*txhi, q1l=rb.y*bylo, q1h=rb.y*byhi;
                float p2l=ra.z*txlo, p2h=ra.z*txhi, q2l=rb.z*bylo, q2h=rb.z*byhi;
                float c0x = fmaxf(p0l,p0h) + fmaxf(q0l,q0h) + rc.x;
                float c1x = fmaxf(p1l,p1h) + fmaxf(q1l,q1h) + rc.y;
                float c2x = fmaxf(p2l,p2h) + fmaxf(q2l,q2h) + rc.z;
                float c0n = fminf(p0l,p0h) + fminf(q0l,q0h) + rc.x;
                float c1n = fminf(p1l,p1h) + fminf(q1l,q1h) + rc.y;
                float c2n = fminf(p2l,p2h) + fminf(q2l,q2h) + rc.z;
                float zmn = fminf(ra.w*txlo, ra.w*txhi) + fminf(rb.w*bylo, rb.w*byhi) + rc.w;
                pass = (fminf(fminf(c0x, c1x), c2x) >= -1e-5f) & (zmn < h);
                full = (fminf(fminf(c0n, c1n), c2n) >= 1e-5f);
            }
            unsigned long long mp = __ballot(pass && !full);
            unsigned long long mf = __ballot(pass && full);
            int cp = __popcll(mp);
            int cf = __popcll(mf);
            if (pass && !full) {
                int sl = wbase + __popcll(mp & ((1ull << lane) - 1ull));
                sA[sl] = ra; sB[sl] = rb; sC[sl] = rc;
            }
            // full-cover: depth-plane-only eval via readlane broadcast (no LDS)
            unsigned long long w = mf;
            while (w) {
                int l = __builtin_amdgcn_readfirstlane(__ffsll((unsigned long long)w) - 1);
                w &= w - 1ull;
                float gxw = __int_as_float(__builtin_amdgcn_readlane(__float_as_int(ra.w), l));
                float gyw = __int_as_float(__builtin_amdgcn_readlane(__float_as_int(rb.w), l));
                float aaw = __int_as_float(__builtin_amdgcn_readlane(__float_as_int(rc.w), l));
                float e3 = fmaf(gyw, yp, aaw);
                #pragma unroll
                for (int jj = 0; jj < 4; ++jj)
                    m[jj] = fminf(m[jj], fmaf(gxw, xp[jj], e3));
            }
            // partial: LDS-compacted loop (depth-1 prefetch), R5-proven body
            if (cp > 0) {
                v4f gx = sA[wbase], gy = sB[wbase], aa = sC[wbase];
                for (int i = 0; i < cp; ++i) {
                    v4f nx = sA[wbase+i+1], ny = sB[wbase+i+1], nzv = sC[wbase+i+1];
                    float e0 = fmaf(gy.x, yp, aa.x);
                    float e1 = fmaf(gy.y, yp, aa.y);
                    float e2 = fmaf(gy.z, yp, aa.z);
                    float e3 = fmaf(gy.w, yp, aa.w);
                    #pragma unroll
                    for (int jj = 0; jj < 4; ++jj) {
                        float n0 = fmaf(gx.x, xp[jj], e0);
                        float n1 = fmaf(gx.y, xp[jj], e1);
                        float n2 = fmaf(gx.z, xp[jj], e2);
                        float n3 = fmaf(gx.w, xp[jj], e3);
                        float q = fminf(fminf(n0, n1), n2);
                        m[jj] = fminf(m[jj], (q >= 0.0f) ? n3 : BIGF);
                    }
                    gx = nx; gy = ny; aa = nzv;
                }
            }
            if (cp + cf > 0)
                h = fminf(h, wave_max_dpp(fmaxf(fmaxf(m[0], m[1]), fmaxf(m[2], m[3]))));
            pc = pn; vc = vn;
            pn = p2w; vn = v2;
        }
    }
    // epilogue: transform + row flip + filtered atomicMin into d_out
    #pragma unroll
    for (int jj = 0; jj < 4; ++jj) {
        if (m[jj] < 9.99f) {
            float depth = 1.0f / (10.0f - m[jj]);
            unsigned int mv = __float_as_uint(depth);
            unsigned int cv = outz[zo + jj];
            if (mv < cv) atomicMin(&outz[zo + jj], mv);
        }
    }
}

// ---------------- fallback: R5 scan raster (if ws too small for bins) ---------
__global__ __launch_bounds__(256) void k_raster_scan(const v4f* __restrict__ fd,
                                                     const v4f* __restrict__ bb,
                                                     unsigned int* __restrict__ outz,
                                                     int B, int F) {
    __shared__ v4f sA[257], sB[257], sC[257];
    int tid = threadIdx.x, lane = tid & 63, wave = tid >> 6;
    int wbase = wave << 6;
    int j = blockIdx.x >> 4;
    int s = blockIdx.x & (SUBSPLIT-1);
    int nTB = TILES * B;
    int f_begin = (s * F) / SUBSPLIT, f_end = ((s + 1) * F) / SUBSPLIT;

    #pragma unroll 1
    for (int phase = 0; phase < 2; ++phase) {
        int tb = (phase == 0) ? j : (nTB - 1 - j);
        int rank = tb / B;
        int b = tb - rank * B;
        int tx, ty;
        rank_to_tile(rank, tx, ty);
        int rowbase = ty*TH + wave*8;
        int row = rowbase + (lane >> 3);
        int col = tx*TW + (lane & 7) * 4;
        float yp = ndc(row);
        float xp[4];
        #pragma unroll
        for (int jj = 0; jj < 4; ++jj) xp[jj] = ndc(col + jj);
        float txlo = ndc(tx*TW), txhi = ndc(tx*TW + TW - 1);
        float bylo = ndc(rowbase), byhi = ndc(rowbase + 7);
        float m[4] = {BIGF, BIGF, BIGF, BIGF};
        float h = 9.99f;

        const v4f* bbp = bb + (size_t)b * F;
        const v4f* fdp = fd + (size_t)b * F * 3;

        v4f box = bbp[min(f_begin + lane, f_end - 1)];
        bool valid = (f_begin + lane) < f_end;

        for (int g0 = f_begin; g0 < f_end; g0 += 64) {
            int fn = g0 + 64 + lane;
            v4f nbox = bbp[min(fn, f_end - 1)];
            bool nvalid = fn < f_end;

            bool pass = valid &
                        (box.x <= txhi) & (box.y >= txlo) &
                        (box.z <= byhi) & (box.w >= bylo);
            v4f ra, rb, rc;
            if (pass) {
                int f = g0 + lane;
                ra = fdp[3*f]; rb = fdp[3*f+1]; rc = fdp[3*f+2];
                pass = tile_test(ra, rb, rc, txlo, txhi, bylo, byhi)
                    && (plane_min(ra.w, rb.w, rc.w, txlo, txhi, bylo, byhi) < h);
            }
            unsigned long long mk = __ballot(pass);
            int total = __popcll(mk);
            if (pass) {
                int slot = wbase + __popcll(mk & ((1ull << lane) - 1ull));
                sA[slot] = ra;
                sB[slot] = rb;
                sC[slot] = rc;
            }
            if (total > 0) {
                v4f gx = sA[wbase], gy = sB[wbase], aa = sC[wbase];
                for (int i = 0; i < total; ++i) {
                    v4f nx = sA[wbase+i+1], ny = sB[wbase+i+1], nzv = sC[wbase+i+1];
                    float e0 = fmaf(gy.x, yp, aa.x);
                    float e1 = fmaf(gy.y, yp, aa.y);
                    float e2 = fmaf(gy.z, yp, aa.z);
                    float e3 = fmaf(gy.w, yp, aa.w);
                    #pragma unroll
                    for (int jj = 0; jj < 4; ++jj) {
                        float n0 = fmaf(gx.x, xp[jj], e0);
                        float n1 = fmaf(gx.y, xp[jj], e1);
                        float n2 = fmaf(gx.z, xp[jj], e2);
                        float n3 = fmaf(gx.w, xp[jj], e3);
                        float q = fminf(fminf(n0, n1), n2);
                        m[jj] = fminf(m[jj], (q >= 0.0f) ? n3 : BIGF);
                    }
                    gx = nx; gy = ny; aa = nzv;
                }
                h = fminf(9.99f, wave_max_dpp(fmaxf(fmaxf(m[0], m[1]), fmaxf(m[2], m[3]))));
            }
            box = nbox; valid = nvalid;
        }
        int orow = IMG - 1 - row;
        size_t zo = (size_t)b * (IMG*IMG) + (size_t)orow * IMG + col;
        #pragma unroll
        for (int jj = 0; jj < 4; ++jj) {
            if (m[jj] < 9.99f) {
                float depth = 1.0f / (10.0f - m[jj]);
                unsigned int mv = __float_as_uint(depth);
                unsigned int cv = outz[zo + jj];
                if (mv < cv) atomicMin(&outz[zo + jj], mv);
            }
        }
    }
}

extern "C" void kernel_launch(void* const* d_in, const int* in_sizes, int n_in,
                              void* d_out, int out_size, void* d_ws, size_t ws_size,
                              hipStream_t stream) {
    const float* verts = (const float*)d_in[0];
    const int*   faces = (const int*)d_in[1];
    const float* Km    = (const float*)d_in[2];
    const float* Rm    = (const float*)d_in[3];
    const float* tm    = (const float*)d_in[4];
    const float* dm    = (const float*)d_in[5];
    float* out = (float*)d_out;

    int B = in_sizes[2] / 9;
    int V = in_sizes[0] / (3 * B);
    int F = in_sizes[1] / (3 * B);
    int nz = B * IMG * IMG;
    int nbins = TILES * B;

    char* ws = (char*)d_ws;
    size_t al = 255;
    size_t o_fd  = 0;
    size_t o_bb  = (o_fd + (size_t)B*F*48 + al) & ~al;
    size_t o_kz  = (o_bb + (size_t)B*F*16 + al) & ~al;
    size_t o_cnt = (o_kz + (size_t)B*F*4 + al) & ~al;
    size_t o_ids = (o_cnt + (size_t)nbins*8 + al) & ~al;
    size_t need_bins = o_ids + (size_t)nbins * F * 4;   // fixed bin regions, exact capacity
    size_t need_scan = o_cnt;

    v4f* fd  = (v4f*)(ws + o_fd);
    v4f* bbp = (v4f*)(ws + o_bb);
    float* keyz = (float*)(ws + o_kz);
    unsigned int* gcnt = (unsigned int*)(ws + o_cnt);
    unsigned int* ids  = (unsigned int*)(ws + o_ids);

    int projBlocks = (B*F + 63) / 64;
    int binBlocks  = (B*F + 255) / 256;

    // packed-id format requires id < 2^28
    if (ws_size >= need_bins && nbins <= 1024 && (size_t)B*F < (1u<<28)) {
        hipMemsetAsync(gcnt, 0, (size_t)nbins*8, stream);
        k_proj<<<projBlocks + 256, 64, 0, stream>>>(verts, faces, Km, Rm, tm, dm,
                                                    fd, bbp, keyz, (unsigned int*)out,
                                                    B, V, F, nz, projBlocks);
        k_bin<<<binBlocks, 256, 0, stream>>>(fd, bbp, keyz, ids, gcnt, B, F);
        int rasterBlocks = nbins * RSUB;              // B=4 -> 2048, heavy-first
        k_raster<<<rasterBlocks, 256, 0, stream>>>(fd, ids, gcnt,
                                                   (unsigned int*)out, B, F);
    } else if (ws_size >= need_scan) {
        k_proj<<<projBlocks + 256, 64, 0, stream>>>(verts, faces, Km, Rm, tm, dm,
                                                    fd, bbp, keyz, (unsigned int*)out,
                                                    B, V, F, nz, projBlocks);
        int rasterBlocks = (TILES * B / 2) * SUBSPLIT;
        k_raster_scan<<<rasterBlocks, 256, 0, stream>>>(fd, bbp, (unsigned int*)out, B, F);
    }
}

// Round 18
// 115.590 us; speedup vs baseline: 1.2956x; 1.0317x over previous
//
#include <hip/hip_runtime.h>

#define IMG 256
#define TW 32
#define TH 32
#define TILES 64           // 8x8 tiles
#define SUBSPLIT 16        // scan-fallback substreams per tile
#define RSUB 8             // binned substreams per tile-b (R10-proven best)
#define ZTHR 9.5f          // near/far class threshold on depth key (10 - zinv)
#define BIGF 1e30f

typedef float v4f __attribute__((ext_vector_type(4)));

__device__ __forceinline__ float ndc(int i) { return (2.0f*i + 1.0f - IMG) * (1.0f/IMG); }

// center-out ring walk over the 8x8 tile grid: rank 0..63 -> (tx,ty)
__device__ __forceinline__ void rank_to_tile(int rank, int& tx, int& ty) {
    int k, base;
    if (rank < 4)       { k = 0; base = 0;  }
    else if (rank < 16) { k = 1; base = 4;  }
    else if (rank < 36) { k = 2; base = 16; }
    else                { k = 3; base = 36; }
    int j = rank - base;
    int s = 2*k + 2;
    int seg = j / (s - 1);
    int off = j - seg * (s - 1);
    int lo = 3 - k, hi = 4 + k;
    if      (seg == 0) { tx = lo + off; ty = lo; }
    else if (seg == 1) { tx = hi;       ty = lo + off; }
    else if (seg == 2) { tx = hi - off; ty = hi; }
    else               { tx = lo;       ty = hi - off; }
}

// conservative rect-vs-face test (edges 0..2): max of edge plane over rect corners
__device__ __forceinline__ bool tile_test(v4f gx, v4f gy, v4f a,
                                          float txlo, float txhi, float tylo, float tyhi) {
    float m0 = fmaxf(gx.x*txlo, gx.x*txhi) + fmaxf(gy.x*tylo, gy.x*tyhi) + a.x;
    float m1 = fmaxf(gx.y*txlo, gx.y*txhi) + fmaxf(gy.y*tylo, gy.y*tyhi) + a.y;
    float m2 = fmaxf(gx.z*txlo, gx.z*txhi) + fmaxf(gy.z*tylo, gy.z*tyhi) + a.z;
    return fminf(fminf(m0, m1), m2) >= -1e-5f;
}

// min of affine plane over pixel-center rect
__device__ __forceinline__ float plane_min(float gw, float hw, float aw,
                                           float xlo, float xhi, float ylo, float yhi) {
    return fminf(gw*xlo, gw*xhi) + fminf(hw*ylo, hw*yhi) + aw;
}

// full-wave (64-lane) max via DPP — VALU-pipe only (R5-proven)
__device__ __forceinline__ float wave_max_dpp(float v) {
    int x;
    x = __builtin_amdgcn_update_dpp(0, __float_as_int(v), 0x111, 0xF, 0xF, true);
    v = fmaxf(v, __int_as_float(x));
    x = __builtin_amdgcn_update_dpp(0, __float_as_int(v), 0x112, 0xF, 0xF, true);
    v = fmaxf(v, __int_as_float(x));
    x = __builtin_amdgcn_update_dpp(0, __float_as_int(v), 0x114, 0xF, 0xF, true);
    v = fmaxf(v, __int_as_float(x));
    x = __builtin_amdgcn_update_dpp(0, __float_as_int(v), 0x118, 0xF, 0xF, true);
    v = fmaxf(v, __int_as_float(x));
    x = __builtin_amdgcn_update_dpp(0, __float_as_int(v), 0x142, 0xF, 0xF, true);
    v = fmaxf(v, __int_as_float(x));
    x = __builtin_amdgcn_update_dpp(0, __float_as_int(v), 0x143, 0xF, 0xF, true);
    v = fmaxf(v, __int_as_float(x));
    return __int_as_float(__builtin_amdgcn_readlane(__float_as_int(v), 63));
}

// conservative tile-cover mask (bit t = ty*8+tx) from pixel bbox + edge tests
__device__ __forceinline__ unsigned long long cover_mask_px(int i0, int i1, int j0, int j1,
                                                            v4f gx, v4f gy, v4f aa) {
    if (i0 > 255 || i1 < 0 || j0 > 255 || j1 < 0) return 0ull;
    int tx0 = max(i0, 0) >> 5, tx1 = min(i1, 255) >> 5;
    int ty0 = max(j0, 0) >> 5, ty1 = min(j1, 255) >> 5;
    unsigned long long m = 0ull;
    for (int ty = ty0; ty <= ty1; ++ty) {
        float tylo = ndc(ty*TH), tyhi = ndc(ty*TH + TH - 1);
        for (int tx = tx0; tx <= tx1; ++tx) {
            if (tile_test(gx, gy, aa, ndc(tx*TW), ndc(tx*TW + TW - 1), tylo, tyhi))
                m |= 1ull << (ty*8 + tx);
        }
    }
    return m;
}

// ---------------- fused prep: face setup + binning (near/far) | out init ------
// Bin region = ids[bin*F .. bin*F+F): NEAR ids (face depth key < ZTHR) written
// from the FRONT, FAR ids from the BACK. Counts in gcnt[bin*2+{0,1}]. Exact
// partition -> capacity still F; NO contended global atomics (R12/R14 lesson).
// Entry packed: id|(blo<<28)|(bhi<<30).
__global__ void k_prep(const float* __restrict__ verts, const int* __restrict__ faces,
                       const float* __restrict__ Km, const float* __restrict__ Rm,
                       const float* __restrict__ tm, const float* __restrict__ dm,
                       v4f* __restrict__ fd, v4f* __restrict__ bb,
                       unsigned int* __restrict__ ids,
                       unsigned int* __restrict__ outz, unsigned int* __restrict__ gcnt,
                       int B, int V, int F, int nz, int faceBlocks, int doBins) {
    if ((int)blockIdx.x >= faceBlocks) {
        int idx = (blockIdx.x - faceBlocks) * 256 + threadIdx.x;
        int stride = (gridDim.x - faceBlocks) * 256;
        for (int j = idx; j < nz; j += stride) outz[j] = 0x42C80000u;  // 100.0f (far)
        return;
    }
    __shared__ int lcnt[2048];
    __shared__ unsigned int lbase[2048];
    __shared__ int lofs[2048];
    int nbins = TILES * B;
    int tid = threadIdx.x;
    if (doBins) {
        for (int k = tid; k < 2*nbins; k += 256) { lcnt[k] = 0; lofs[k] = 0; }
        __syncthreads();
    }
    int i = blockIdx.x * 256 + tid;
    bool alive = i < B * F;
    unsigned long long tmask = 0ull;
    int b = 0, j0c = 0, j1c = 0, cls = 0;
    if (alive) {
        b = i / F;
        const float* vb = verts + (size_t)b * V * 3;
        const float* R = Rm + b * 9;
        const float* K = Km + b * 9;
        const float* t = tm + b * 3;
        const float* d = dm + b * 5;
        float X[3], Y[3], Z[3];
        float maxzi = 0.0f;
        #pragma unroll
        for (int c = 0; c < 3; ++c) {
            int vi = faces[3*i + c];
            float px = vb[3*vi], py = vb[3*vi+1], pz = vb[3*vi+2];
            float x = R[0]*px + R[1]*py + R[2]*pz + t[0];
            float y = R[3]*px + R[4]*py + R[5]*pz + t[1];
            float z = R[6]*px + R[7]*py + R[8]*pz + t[2];
            float iz = 1.0f / (z + 1e-9f);
            maxzi = fmaxf(maxzi, iz);
            float x_ = x * iz, y_ = y * iz;
            float k1 = d[0], k2 = d[1], p1 = d[2], p2 = d[3], k3 = d[4];
            float r2 = x_*x_ + y_*y_;
            float rad = 1.0f + k1*r2 + k2*r2*r2 + k3*r2*r2*r2;
            float xd = x_*rad + 2.0f*p1*x_*y_ + p2*(r2 + 2.0f*x_*x_);
            float yd = y_*rad + p1*(r2 + 2.0f*y_*y_) + 2.0f*p2*x_*y_;
            float u  = K[0]*xd + K[1]*yd + K[2];
            float vc = K[3]*xd + K[4]*yd + K[5];
            vc = 1024.0f - vc;
            X[c] = (u  - 512.0f) * (1.0f/512.0f);
            Y[c] = (vc - 512.0f) * (1.0f/512.0f);
            Z[c] = z;
        }
        float x0=X[0], y0=Y[0], z0=Z[0], x1=X[1], y1=Y[1], z1=Z[1], x2=X[2], y2=Y[2], z2=Z[2];
        float denom = (y1-y2)*(x0-x2) + (x2-x1)*(y0-y2);
        bool ok = (fabsf(denom) > 1e-8f) && (z0 > 1e-8f) && (z1 > 1e-8f) && (z2 > 1e-8f);
        if (!ok) {
            bb[i] = (v4f){3e38f, -3e38f, 3e38f, -3e38f};
        } else {
            float s = (denom > 0.0f) ? 1.0f : -1.0f;
            float absd = fabsf(denom);
            float P0x = s*(y1-y2), P0y = s*(x2-x1);
            float P1x = s*(y2-y0), P1y = s*(x0-x2);
            float P2x = -(P0x + P1x), P2y = -(P0y + P1y);
            float A0 = -(P0x*x2 + P0y*y2);
            float A1 = -(P1x*x2 + P1y*y2);
            float A2 = absd - A0 - A1;
            float ia  = 1.0f / absd;
            float rz0 = ia / z0, rz1 = ia / z1, rz2 = ia / z2;
            float zix = P0x*rz0 + P1x*rz1 + P2x*rz2;
            float ziy = P0y*rz0 + P1y*rz1 + P2y*rz2;
            float zic = A0*rz0 + A1*rz1 + A2*rz2;
            v4f ga = (v4f){P0x, P1x, P2x, -zix};
            v4f gb = (v4f){P0y, P1y, P2y, -ziy};
            v4f gc = (v4f){A0,  A1,  A2,  10.0f - zic};
            fd[(size_t)i*3 + 0] = ga;
            fd[(size_t)i*3 + 1] = gb;
            fd[(size_t)i*3 + 2] = gc;
            float xmn = fminf(x0, fminf(x1, x2)) - 1e-4f;
            float xmx = fmaxf(x0, fmaxf(x1, x2)) + 1e-4f;
            float ymn = fminf(y0, fminf(y1, y2)) - 1e-4f;
            float ymx = fmaxf(y0, fmaxf(y1, y2)) + 1e-4f;
            bb[i] = (v4f){xmn, xmx, ymn, ymx};
            if (doBins) {
                int i0 = (int)floorf(xmn*128.0f + 127.5f);
                int i1 = (int)ceilf (xmx*128.0f + 127.5f);
                int j0 = (int)floorf(ymn*128.0f + 127.5f);
                int j1 = (int)ceilf (ymx*128.0f + 127.5f);
                tmask = cover_mask_px(i0, i1, j0, j1, ga, gb, gc);
                j0c = max(j0, 0); j1c = min(j1, 255);
                // face nearest depth key (zinv affine -> max at a vertex, exact)
                cls = ((10.0f - maxzi) < ZTHR) ? 0 : 1;   // 0 = near, 1 = far
            }
        }
    }
    if (doBins) {
        unsigned long long mk = tmask;
        while (mk) {
            int t = __builtin_ctzll(mk); mk &= mk - 1ull;
            atomicAdd(&lcnt[(t*B + b)*2 + cls], 1);
        }
        __syncthreads();
        for (int k = tid; k < 2*nbins; k += 256)
            if (lcnt[k]) lbase[k] = atomicAdd(&gcnt[k], (unsigned int)lcnt[k]);
        __syncthreads();
        mk = tmask;
        while (mk) {
            int t = __builtin_ctzll(mk); mk &= mk - 1ull;
            int ty = t >> 3;
            int bin = t*B + b;
            unsigned int blo = (unsigned int)max((j0c >> 3) - ty*4, 0);
            unsigned int bhi = (unsigned int)min((j1c >> 3) - ty*4, 3);
            unsigned int pack = (unsigned int)i | (blo << 28) | (bhi << 30);
            int key = bin*2 + cls;
            int sl = atomicAdd(&lofs[key], 1);
            unsigned int pos = lbase[key] + (unsigned int)sl;
            size_t idx = (cls == 0) ? ((size_t)bin*F + pos)               // near: front
                                    : ((size_t)bin*F + (F - 1) - pos);    // far: back
            ids[idx] = pack;
        }
    }
}

// ---------------- binned band raster (R13: front-to-back segments) -----------
// R10 structure (RSUB=8 split, packed band word, full-cover readlane path,
// partial LDS loop, outz hi-Z seed). R13: each block processes its NEAR
// slice first, then its FAR slice, carrying h (and m) across — the per-group
// DPP refresh makes h tight after the near groups, so the proven zmn<h test
// culls far candidates before gather/eval. Order-only change: output exact.
__global__ __launch_bounds__(256) void k_raster(const v4f* __restrict__ fd,
                                                const unsigned int* __restrict__ ids,
                                                const unsigned int* __restrict__ gcnt,
                                                unsigned int* __restrict__ outz,
                                                int B, int F) {
    __shared__ v4f sA[257], sB[257], sC[257];
    int tid = threadIdx.x, lane = tid & 63, wave = tid >> 6;
    int wbase = wave << 6;
    int tbIdx = blockIdx.x >> 3;          // heavy-first: low rank = low bid
    int sub = blockIdx.x & (RSUB-1);
    int rank = tbIdx / B;
    int b = tbIdx - rank * B;
    int tx, ty;
    rank_to_tile(rank, tx, ty);
    int bin = (ty*8 + tx)*B + b;
    unsigned int lnN = gcnt[bin*2 + 0];
    unsigned int lnF = gcnt[bin*2 + 1];
    size_t base = (size_t)bin * F;

    int rowbase = ty*TH + wave*8;
    int row = rowbase + (lane >> 3);
    int col = tx*TW + (lane & 7) * 4;
    float yp = ndc(row);
    float xp[4];
    #pragma unroll
    for (int jj = 0; jj < 4; ++jj) xp[jj] = ndc(col + jj);
    float txlo = ndc(tx*TW), txhi = ndc(tx*TW + TW - 1);
    float bylo = ndc(rowbase), byhi = ndc(rowbase + 7);
    float m[4] = {BIGF, BIGF, BIGF, BIGF};

    int orow = IMG - 1 - row;
    size_t zo = (size_t)b * (IMG*IMG) + (size_t)orow * IMG + col;

    // hi-Z seed from current output (any published value is a valid bound)
    float hs = 0.0f;
    #pragma unroll
    for (int jj = 0; jj < 4; ++jj) {
        float d = __uint_as_float(outz[zo + jj]);
        hs = fmaxf(hs, 10.0f - 1.0f/d);
    }
    float h = fminf(9.99f, wave_max_dpp(hs) + 1e-4f);

    #pragma unroll 1
    for (int seg = 0; seg < 2; ++seg) {
        unsigned int segLen = (seg == 0) ? lnN : lnF;
        unsigned int segOff = (seg == 0) ? 0u : (unsigned int)F - lnF;
        unsigned int p0 = segOff + (unsigned int)(((unsigned long long)sub     * segLen) / RSUB);
        unsigned int p1 = segOff + (unsigned int)(((unsigned long long)(sub+1) * segLen) / RSUB);
        if (p1 <= p0) continue;

        unsigned int pc = ids[base + min(p0 + lane, p1 - 1)];
        bool vc = (p0 + lane) < p1;
        unsigned int pn = ids[base + min(p0 + 64 + lane, p1 - 1)];
        bool vn = (p0 + 64 + lane) < p1;

        for (unsigned int p = p0; p < p1; p += 64) {
            unsigned int p2w = ids[base + min(p + 128 + lane, p1 - 1)];
            bool v2 = (p + 128 + lane) < p1;

            // band test from packed word: 2 int compares, no memory
            unsigned int blo = (pc >> 28) & 3u, bhi = pc >> 30;
            unsigned int idc = pc & 0x0FFFFFFFu;
            bool pass = vc & ((int)blo <= wave) & ((int)bhi >= wave);
            bool full = false;
            v4f ra = (v4f){0,0,0,0}, rb = (v4f){0,0,0,0}, rc = (v4f){0,0,0,0};
            if (pass) {
                ra = fd[(size_t)idc*3]; rb = fd[(size_t)idc*3+1]; rc = fd[(size_t)idc*3+2];
                float p0l=ra.x*txlo, p0h=ra.x*txhi, q0l=rb.x*bylo, q0h=rb.x*byhi;
                float p1l=ra.y*txlo, p1h=ra.y*txhi, q1l=rb.y*bylo, q1h=rb.y*byhi;
                float p2l=ra.z*txlo, p2h=ra.z*txhi, q2l=rb.z*bylo, q2h=rb.z*byhi;
                float c0x = fmaxf(p0l,p0h) + fmaxf(q0l,q0h) + rc.x;
                float c1x = fmaxf(p1l,p1h) + fmaxf(q1l,q1h) + rc.y;
                float c2x = fmaxf(p2l,p2h) + fmaxf(q2l,q2h) + rc.z;
                float c0n = fminf(p0l,p0h) + fminf(q0l,q0h) + rc.x;
                float c1n = fminf(p1l,p1h) + fminf(q1l,q1h) + rc.y;
                float c2n = fminf(p2l,p2h) + fminf(q2l,q2h) + rc.z;
                float zmn = fminf(ra.w*txlo, ra.w*txhi) + fminf(rb.w*bylo, rb.w*byhi) + rc.w;
                pass = (fminf(fminf(c0x, c1x), c2x) >= -1e-5f) & (zmn < h);
                full = (fminf(fminf(c0n, c1n), c2n) >= 1e-5f);
            }
            unsigned long long mp = __ballot(pass && !full);
            unsigned long long mf = __ballot(pass && full);
            int cp = __popcll(mp);
            int cf = __popcll(mf);
            if (pass && !full) {
                int sl = wbase + __popcll(mp & ((1ull << lane) - 1ull));
                sA[sl] = ra; sB[sl] = rb; sC[sl] = rc;
            }
            // full-cover: depth-plane-only eval via readlane broadcast (no LDS)
            unsigned long long w = mf;
            while (w) {
                int l = __builtin_amdgcn_readfirstlane(__ffsll((unsigned long long)w) - 1);
                w &= w - 1ull;
                float gxw = __int_as_float(__builtin_amdgcn_readlane(__float_as_int(ra.w), l));
                float gyw = __int_as_float(__builtin_amdgcn_readlane(__float_as_int(rb.w), l));
                float aaw = __int_as_float(__builtin_amdgcn_readlane(__float_as_int(rc.w), l));
                float e3 = fmaf(gyw, yp, aaw);
                #pragma unroll
                for (int jj = 0; jj < 4; ++jj)
                    m[jj] = fminf(m[jj], fmaf(gxw, xp[jj], e3));
            }
            // partial: LDS-compacted loop (depth-1 prefetch), R5-proven body
            if (cp > 0) {
                v4f gx = sA[wbase], gy = sB[wbase], aa = sC[wbase];
                for (int i = 0; i < cp; ++i) {
                    v4f nx = sA[wbase+i+1], ny = sB[wbase+i+1], nzv = sC[wbase+i+1];
                    float e0 = fmaf(gy.x, yp, aa.x);
                    float e1 = fmaf(gy.y, yp, aa.y);
                    float e2 = fmaf(gy.z, yp, aa.z);
                    float e3 = fmaf(gy.w, yp, aa.w);
                    #pragma unroll
                    for (int jj = 0; jj < 4; ++jj) {
                        float n0 = fmaf(gx.x, xp[jj], e0);
                        float n1 = fmaf(gx.y, xp[jj], e1);
                        float n2 = fmaf(gx.z, xp[jj], e2);
                        float n3 = fmaf(gx.w, xp[jj], e3);
                        float q = fminf(fminf(n0, n1), n2);
                        m[jj] = fminf(m[jj], (q >= 0.0f) ? n3 : BIGF);
                    }
                    gx = nx; gy = ny; aa = nzv;
                }
            }
            if (cp + cf > 0)
                h = fminf(h, wave_max_dpp(fmaxf(fmaxf(m[0], m[1]), fmaxf(m[2], m[3]))));
            pc = pn; vc = vn;
            pn = p2w; vn = v2;
        }
    }
    // epilogue: transform + row flip + filtered atomicMin into d_out
    #pragma unroll
    for (int jj = 0; jj < 4; ++jj) {
        if (m[jj] < 9.99f) {
            float depth = 1.0f / (10.0f - m[jj]);
            unsigned int mv = __float_as_uint(depth);
            unsigned int cv = outz[zo + jj];
            if (mv < cv) atomicMin(&outz[zo + jj], mv);
        }
    }
}

// ---------------- fallback: R5 scan raster (if ws too small for bins) ---------
__global__ __launch_bounds__(256) void k_raster_scan(const v4f* __restrict__ fd,
                                                     const v4f* __restrict__ bb,
                                                     unsigned int* __restrict__ outz,
                                                     int B, int F) {
    __shared__ v4f sA[257], sB[257], sC[257];
    int tid = threadIdx.x, lane = tid & 63, wave = tid >> 6;
    int wbase = wave << 6;
    int j = blockIdx.x >> 4;
    int s = blockIdx.x & (SUBSPLIT-1);
    int nTB = TILES * B;
    int f_begin = (s * F) / SUBSPLIT, f_end = ((s + 1) * F) / SUBSPLIT;

    #pragma unroll 1
    for (int phase = 0; phase < 2; ++phase) {
        int tb = (phase == 0) ? j : (nTB - 1 - j);
        int rank = tb / B;
        int b = tb - rank * B;
        int tx, ty;
        rank_to_tile(rank, tx, ty);
        int rowbase = ty*TH + wave*8;
        int row = rowbase + (lane >> 3);
        int col = tx*TW + (lane & 7) * 4;
        float yp = ndc(row);
        float xp[4];
        #pragma unroll
        for (int jj = 0; jj < 4; ++jj) xp[jj] = ndc(col + jj);
        float txlo = ndc(tx*TW), txhi = ndc(tx*TW + TW - 1);
        float bylo = ndc(rowbase), byhi = ndc(rowbase + 7);
        float m[4] = {BIGF, BIGF, BIGF, BIGF};
        float h = 9.99f;

        const v4f* bbp = bb + (size_t)b * F;
        const v4f* fdp = fd + (size_t)b * F * 3;

        v4f box = bbp[min(f_begin + lane, f_end - 1)];
        bool valid = (f_begin + lane) < f_end;

        for (int g0 = f_begin; g0 < f_end; g0 += 64) {
            int fn = g0 + 64 + lane;
            v4f nbox = bbp[min(fn, f_end - 1)];
            bool nvalid = fn < f_end;

            bool pass = valid &
                        (box.x <= txhi) & (box.y >= txlo) &
                        (box.z <= byhi) & (box.w >= bylo);
            v4f ra, rb, rc;
            if (pass) {
                int f = g0 + lane;
                ra = fdp[3*f]; rb = fdp[3*f+1]; rc = fdp[3*f+2];
                pass = tile_test(ra, rb, rc, txlo, txhi, bylo, byhi)
                    && (plane_min(ra.w, rb.w, rc.w, txlo, txhi, bylo, byhi) < h);
            }
            unsigned long long mk = __ballot(pass);
            int total = __popcll(mk);
            if (pass) {
                int slot = wbase + __popcll(mk & ((1ull << lane) - 1ull));
                sA[slot] = ra;
                sB[slot] = rb;
                sC[slot] = rc;
            }
            if (total > 0) {
                v4f gx = sA[wbase], gy = sB[wbase], aa = sC[wbase];
                for (int i = 0; i < total; ++i) {
                    v4f nx = sA[wbase+i+1], ny = sB[wbase+i+1], nzv = sC[wbase+i+1];
                    float e0 = fmaf(gy.x, yp, aa.x);
                    float e1 = fmaf(gy.y, yp, aa.y);
                    float e2 = fmaf(gy.z, yp, aa.z);
                    float e3 = fmaf(gy.w, yp, aa.w);
                    #pragma unroll
                    for (int jj = 0; jj < 4; ++jj) {
                        float n0 = fmaf(gx.x, xp[jj], e0);
                        float n1 = fmaf(gx.y, xp[jj], e1);
                        float n2 = fmaf(gx.z, xp[jj], e2);
                        float n3 = fmaf(gx.w, xp[jj], e3);
                        float q = fminf(fminf(n0, n1), n2);
                        m[jj] = fminf(m[jj], (q >= 0.0f) ? n3 : BIGF);
                    }
                    gx = nx; gy = ny; aa = nzv;
                }
                h = fminf(9.99f, wave_max_dpp(fmaxf(fmaxf(m[0], m[1]), fmaxf(m[2], m[3]))));
            }
            box = nbox; valid = nvalid;
        }
        int orow = IMG - 1 - row;
        size_t zo = (size_t)b * (IMG*IMG) + (size_t)orow * IMG + col;
        #pragma unroll
        for (int jj = 0; jj < 4; ++jj) {
            if (m[jj] < 9.99f) {
                float depth = 1.0f / (10.0f - m[jj]);
                unsigned int mv = __float_as_uint(depth);
                unsigned int cv = outz[zo + jj];
                if (mv < cv) atomicMin(&outz[zo + jj], mv);
            }
        }
    }
}

extern "C" void kernel_launch(void* const* d_in, const int* in_sizes, int n_in,
                              void* d_out, int out_size, void* d_ws, size_t ws_size,
                              hipStream_t stream) {
    const float* verts = (const float*)d_in[0];
    const int*   faces = (const int*)d_in[1];
    const float* Km    = (const float*)d_in[2];
    const float* Rm    = (const float*)d_in[3];
    const float* tm    = (const float*)d_in[4];
    const float* dm    = (const float*)d_in[5];
    float* out = (float*)d_out;

    int B = in_sizes[2] / 9;
    int V = in_sizes[0] / (3 * B);
    int F = in_sizes[1] / (3 * B);
    int nz = B * IMG * IMG;
    int nbins = TILES * B;

    char* ws = (char*)d_ws;
    size_t al = 255;
    size_t o_fd  = 0;
    size_t o_bb  = (o_fd + (size_t)B*F*48 + al) & ~al;
    size_t o_cnt = (o_bb + (size_t)B*F*16 + al) & ~al;
    size_t o_ids = (o_cnt + (size_t)nbins*8 + al) & ~al;
    size_t need_bins = o_ids + (size_t)nbins * F * 4;   // fixed bin regions, exact capacity
    size_t need_scan = o_ids;

    v4f* fd  = (v4f*)(ws + o_fd);
    v4f* bbp = (v4f*)(ws + o_bb);
    unsigned int* gcnt = (unsigned int*)(ws + o_cnt);
    unsigned int* ids  = (unsigned int*)(ws + o_ids);

    const int thr = 256;
    int faceBlocks = (B*F + thr - 1) / thr;

    // packed-id format requires id < 2^28
    if (ws_size >= need_bins && nbins <= 1024 && (size_t)B*F < (1u<<28)) {
        hipMemsetAsync(gcnt, 0, (size_t)nbins*8, stream);
        k_prep<<<faceBlocks + 128, thr, 0, stream>>>(verts, faces, Km, Rm, tm, dm,
                                                     fd, bbp, ids, (unsigned int*)out, gcnt,
                                                     B, V, F, nz, faceBlocks, 1);
        int rasterBlocks = nbins * RSUB;              // B=4 -> 2048, heavy-first
        k_raster<<<rasterBlocks, thr, 0, stream>>>(fd, ids, gcnt,
                                                   (unsigned int*)out, B, F);
    } else if (ws_size >= need_scan) {
        k_prep<<<faceBlocks + 128, thr, 0, stream>>>(verts, faces, Km, Rm, tm, dm,
                                                     fd, bbp, ids, (unsigned int*)out, gcnt,
                                                     B, V, F, nz, faceBlocks, 0);
        int rasterBlocks = (TILES * B / 2) * SUBSPLIT;
        k_raster_scan<<<rasterBlocks, thr, 0, stream>>>(fd, bbp, (unsigned int*)out, B, F);
    }
}